// Round 2
// baseline (1975.991 us; speedup 1.0000x reference)
//
#include <hip/hip_runtime.h>
#include <math.h>

#define NB 2048
#define STAGE_SZ (NB * 16 * 2 * 32)  // 2,097,152 floats per p-mean stage

__device__ __forceinline__ float fast_tanh(float x) {
    float ax = fabsf(x);
    float e  = __expf(2.0f * ax);
    float t  = 1.0f - 2.0f / (e + 1.0f);
    return copysignf(t, x);
}

// ---------------------------------------------------------------------------
// p-stream: per walker, all 256 (i,j) pairs; chain p_v through pW0 + 4 residual
// layers, emitting spin-means over i (stage s used by s-layer s).
// pmeans layout: (5, B, 16(j), 2(h), 32)
// launch_bounds(256,1): lift the VGPR cap — p[32]+pn[32] must stay in VGPRs,
// not AGPR spills (R0: VGPR_Count=64 -> ~85K VALU inst/thread from accvgpr
// copies; 603 us).
// ---------------------------------------------------------------------------
__global__ __launch_bounds__(256, 1) void k_pstream(
    const float* __restrict__ r,
    const float* __restrict__ pW0, const float* __restrict__ pb0,
    const float* __restrict__ pW,  const float* __restrict__ pb,
    float* __restrict__ pmeans)
{
    const int b   = blockIdx.x;
    const int tid = threadIdx.x;
    const int i   = tid & 15;   // first index of p_v (reduced over)
    const int j   = tid >> 4;   // second index (kept)
    __shared__ float rl[48];
    if (tid < 48) rl[tid] = r[b * 48 + tid];
    __syncthreads();

    // rr[b,i,j] = r[b,j] - r[b,i]; eye adds 1 to each comp on diagonal (len only)
    float dx = rl[j * 3 + 0] - rl[i * 3 + 0];
    float dy = rl[j * 3 + 1] - rl[i * 3 + 1];
    float dz = rl[j * 3 + 2] - rl[i * 3 + 2];
    float ee = (i == j) ? 1.0f : 0.0f;
    float len = sqrtf((dx + ee) * (dx + ee) + (dy + ee) * (dy + ee) + (dz + ee) * (dz + ee));

    float p[32];
#pragma unroll
    for (int k = 0; k < 32; ++k) p[k] = pb0[k];
    {
        float in4[4] = {dx, dy, dz, len};
#pragma unroll
        for (int m = 0; m < 4; ++m) {
            float x = in4[m];
            const float* Wrow = pW0 + m * 32;   // wave-uniform row -> s_load
#pragma unroll
            for (int k = 0; k < 32; ++k) p[k] += x * Wrow[k];
        }
    }
#pragma unroll
    for (int k = 0; k < 32; ++k) p[k] = fast_tanh(p[k]);

    // stage 0 means (p after pW0): mean over i within each spin-half
#pragma unroll
    for (int k = 0; k < 32; ++k) {
        float v = p[k];
        v += __shfl_xor(v, 1);
        v += __shfl_xor(v, 2);
        v += __shfl_xor(v, 4);
        if ((i & 7) == 0)
            pmeans[(size_t)0 * STAGE_SZ + (size_t)((b * 16 + j) * 2 + (i >> 3)) * 32 + k] = v * 0.125f;
    }
    for (int l = 0; l < 4; ++l) {
        const float* Wl = pW + l * 1024;
        const float* bl = pb + l * 32;
        float pn[32];
#pragma unroll
        for (int k = 0; k < 32; ++k) pn[k] = bl[k];
        // m-outer: weight row Wl[m][0..31] is contiguous + wave-uniform
#pragma unroll
        for (int m = 0; m < 32; ++m) {
            float x = p[m];
            const float* Wrow = Wl + m * 32;
#pragma unroll
            for (int k = 0; k < 32; ++k) pn[k] += x * Wrow[k];
        }
#pragma unroll
        for (int k = 0; k < 32; ++k) {
            p[k] = fast_tanh(pn[k]) + p[k];
            float v = p[k];
            v += __shfl_xor(v, 1);
            v += __shfl_xor(v, 2);
            v += __shfl_xor(v, 4);
            if ((i & 7) == 0)
                pmeans[(size_t)(l + 1) * STAGE_SZ + (size_t)((b * 16 + j) * 2 + (i >> 3)) * 32 + k] = v * 0.125f;
        }
    }
}

// ---------------------------------------------------------------------------
// Layer 0: build s_emb / p_emb means in-block, blk0 (16x56), s_v1 = tanh(blk0@sW0+sb0)
// writes s_v (B,16,256) and smean (B,2,256)
// ---------------------------------------------------------------------------
__global__ __launch_bounds__(256) void k_s0(
    const float* __restrict__ r, const float* __restrict__ a,
    const float* __restrict__ sW0, const float* __restrict__ sb0,
    float* __restrict__ s_v, float* __restrict__ smean)
{
    const int b   = blockIdx.x;
    const int tid = threadIdx.x;
    __shared__ float rl[48];
    __shared__ float al[12];
    __shared__ float pin[16][16][4];  // [j][i][4] = p_v[b,i,j,:]
    __shared__ float se[16][16];      // s_emb
    __shared__ float sm0[2][16];
    __shared__ float pm0[16][2][4];
    __shared__ float blk[16][56];

    if (tid < 48) rl[tid] = r[b * 48 + tid];
    if (tid >= 64 && tid < 76) al[tid - 64] = a[tid - 64];
    __syncthreads();
    {
        const int i = tid & 15, j = tid >> 4;
        float dx = rl[j * 3 + 0] - rl[i * 3 + 0];
        float dy = rl[j * 3 + 1] - rl[i * 3 + 1];
        float dz = rl[j * 3 + 2] - rl[i * 3 + 2];
        float ee = (i == j) ? 1.0f : 0.0f;
        float len = sqrtf((dx + ee) * (dx + ee) + (dy + ee) * (dy + ee) + (dz + ee) * (dz + ee));
        pin[j][i][0] = dx; pin[j][i][1] = dy; pin[j][i][2] = dz; pin[j][i][3] = len;
    }
    if (tid < 16) {
        const int e = tid;
#pragma unroll
        for (int at = 0; at < 4; ++at) {
            float dx = rl[e * 3 + 0] - al[at * 3 + 0];
            float dy = rl[e * 3 + 1] - al[at * 3 + 1];
            float dz = rl[e * 3 + 2] - al[at * 3 + 2];
            float ln = sqrtf(dx * dx + dy * dy + dz * dz);
            se[e][at * 4 + 0] = dx; se[e][at * 4 + 1] = dy;
            se[e][at * 4 + 2] = dz; se[e][at * 4 + 3] = ln;
        }
    }
    __syncthreads();
    if (tid < 32) {
        const int h = tid >> 4, f = tid & 15;
        float s = 0.f;
        for (int e = 0; e < 8; ++e) s += se[h * 8 + e][f];
        sm0[h][f] = s * 0.125f;
    }
    if (tid < 128) {
        const int j = tid >> 3, h = (tid >> 2) & 1, f = tid & 3;
        float s = 0.f;
        for (int i2 = 0; i2 < 8; ++i2) s += pin[j][h * 8 + i2][f];
        pm0[j][h][f] = s * 0.125f;
    }
    __syncthreads();
    for (int t = tid; t < 16 * 56; t += 256) {
        const int e = t / 56, k = t % 56;
        float v;
        if (k < 16)      v = se[e][k];
        else if (k < 32) v = sm0[0][k - 16];
        else if (k < 48) v = sm0[1][k - 32];
        else if (k < 52) v = pm0[e][0][k - 48];
        else             v = pm0[e][1][k - 52];
        blk[e][k] = v;
    }
    __syncthreads();

    const int n = tid;
    float acc[16];
#pragma unroll
    for (int e = 0; e < 16; ++e) acc[e] = sb0[n];
    for (int k = 0; k < 56; k += 4) {
        float w0 = sW0[(k + 0) * 256 + n];
        float w1 = sW0[(k + 1) * 256 + n];
        float w2 = sW0[(k + 2) * 256 + n];
        float w3 = sW0[(k + 3) * 256 + n];
#pragma unroll
        for (int e = 0; e < 16; ++e) {
            float4 s4 = *(const float4*)&blk[e][k];
            acc[e] += s4.x * w0 + s4.y * w1 + s4.z * w2 + s4.w * w3;
        }
    }
    float* sv_b = s_v + (size_t)b * 4096;
    float mu = 0.f, md = 0.f;
#pragma unroll
    for (int e = 0; e < 16; ++e) {
        float v = fast_tanh(acc[e]);
        sv_b[e * 256 + n] = v;
        if (e < 8) mu += v; else md += v;
    }
    smean[(size_t)b * 512 + n]       = mu * 0.125f;
    smean[(size_t)b * 512 + 256 + n] = md * 0.125f;
}

// ---------------------------------------------------------------------------
// Residual / output s-layer. Decomposed blk @ W:
//   W rows [0,256)=s, [256,512)=mu, [512,768)=md, [768,800)=pu, [800,832)=pd
// block = 1 walker, 128 threads.
// Phase 0: thread t computes row-constant sh[c] for c = 2t, 2t+1 -> LDS.
// Phase 1: thread = (electron-half, 4 cols); halves LDS b128 traffic per FMA
// vs the R0 2-col layout.
// ---------------------------------------------------------------------------
__global__ __launch_bounds__(128, 2) void k_slayer(
    const float* __restrict__ W, const float* __restrict__ bias,
    const float* __restrict__ pstage,  // (B,16,2,32) for this layer
    float* __restrict__ s_v, float* __restrict__ smean,
    int residual, int write_means)
{
    const int b   = blockIdx.x;
    const int tid = threadIdx.x;
    __shared__ float sOld[16][256];
    __shared__ float mumd[2][256];
    __shared__ float pupd[16][2][32];
    __shared__ float sh[256];

    const float* sv_b = s_v + (size_t)b * 4096;
    const float* sm_b = smean + (size_t)b * 512;
    const float* ps_b = pstage + (size_t)b * 1024;

    float* sOldF = &sOld[0][0];
    float* mumdF = &mumd[0][0];
    float* pupdF = &pupd[0][0][0];
    for (int t = tid * 4; t < 4096; t += 512)
        *(float4*)&sOldF[t] = *(const float4*)&sv_b[t];
    {
        int t = tid * 4;
        *(float4*)&mumdF[t] = *(const float4*)&sm_b[t];
    }
    for (int t = tid * 4; t < 1024; t += 512)
        *(float4*)&pupdF[t] = *(const float4*)&ps_b[t];
    __syncthreads();

    // ---- phase 0: row-constant part sh[c] = bias + mu@W[256:512] + md@W[512:768]
    {
        const int n0 = tid * 2;
        float sh0 = bias[n0], sh1 = bias[n0 + 1];
        for (int k = 0; k < 256; k += 4) {
            float4 mu4 = *(const float4*)&mumd[0][k];
            float4 md4 = *(const float4*)&mumd[1][k];
            float2 a0 = *(const float2*)&W[(256 + k + 0) * 256 + n0];
            float2 a1 = *(const float2*)&W[(256 + k + 1) * 256 + n0];
            float2 a2 = *(const float2*)&W[(256 + k + 2) * 256 + n0];
            float2 a3 = *(const float2*)&W[(256 + k + 3) * 256 + n0];
            float2 c0 = *(const float2*)&W[(512 + k + 0) * 256 + n0];
            float2 c1 = *(const float2*)&W[(512 + k + 1) * 256 + n0];
            float2 c2 = *(const float2*)&W[(512 + k + 2) * 256 + n0];
            float2 c3 = *(const float2*)&W[(512 + k + 3) * 256 + n0];
            sh0 += mu4.x * a0.x + mu4.y * a1.x + mu4.z * a2.x + mu4.w * a3.x
                 + md4.x * c0.x + md4.y * c1.x + md4.z * c2.x + md4.w * c3.x;
            sh1 += mu4.x * a0.y + mu4.y * a1.y + mu4.z * a2.y + mu4.w * a3.y
                 + md4.x * c0.y + md4.y * c1.y + md4.z * c2.y + md4.w * c3.y;
        }
        sh[n0] = sh0; sh[n0 + 1] = sh1;
    }
    __syncthreads();

    // ---- phase 1: 8 electrons x 4 cols per thread
    const int half = tid >> 6;        // 0: e 0-7, 1: e 8-15
    const int e0   = half * 8;
    const int c0   = (tid & 63) * 4;

    float acc[8][4];
#pragma unroll
    for (int e = 0; e < 8; ++e)
#pragma unroll
        for (int jj = 0; jj < 4; ++jj) acc[e][jj] = 0.f;

    // s part: W rows [0,256)
    for (int k = 0; k < 256; k += 4) {
        float4 w0 = *(const float4*)&W[(k + 0) * 256 + c0];
        float4 w1 = *(const float4*)&W[(k + 1) * 256 + c0];
        float4 w2 = *(const float4*)&W[(k + 2) * 256 + c0];
        float4 w3 = *(const float4*)&W[(k + 3) * 256 + c0];
#pragma unroll
        for (int e = 0; e < 8; ++e) {
            float4 s4 = *(const float4*)&sOld[e0 + e][k];
            acc[e][0] += s4.x * w0.x + s4.y * w1.x + s4.z * w2.x + s4.w * w3.x;
            acc[e][1] += s4.x * w0.y + s4.y * w1.y + s4.z * w2.y + s4.w * w3.y;
            acc[e][2] += s4.x * w0.z + s4.y * w1.z + s4.z * w2.z + s4.w * w3.z;
            acc[e][3] += s4.x * w0.w + s4.y * w1.w + s4.z * w2.w + s4.w * w3.w;
        }
    }
    // p part: rows [768,832)
    for (int k = 0; k < 32; k += 4) {
        float4 u0 = *(const float4*)&W[(768 + k + 0) * 256 + c0];
        float4 u1 = *(const float4*)&W[(768 + k + 1) * 256 + c0];
        float4 u2 = *(const float4*)&W[(768 + k + 2) * 256 + c0];
        float4 u3 = *(const float4*)&W[(768 + k + 3) * 256 + c0];
        float4 d0 = *(const float4*)&W[(800 + k + 0) * 256 + c0];
        float4 d1 = *(const float4*)&W[(800 + k + 1) * 256 + c0];
        float4 d2 = *(const float4*)&W[(800 + k + 2) * 256 + c0];
        float4 d3 = *(const float4*)&W[(800 + k + 3) * 256 + c0];
#pragma unroll
        for (int e = 0; e < 8; ++e) {
            float4 pu4 = *(const float4*)&pupd[e0 + e][0][k];
            float4 pd4 = *(const float4*)&pupd[e0 + e][1][k];
            acc[e][0] += pu4.x * u0.x + pu4.y * u1.x + pu4.z * u2.x + pu4.w * u3.x
                       + pd4.x * d0.x + pd4.y * d1.x + pd4.z * d2.x + pd4.w * d3.x;
            acc[e][1] += pu4.x * u0.y + pu4.y * u1.y + pu4.z * u2.y + pu4.w * u3.y
                       + pd4.x * d0.y + pd4.y * d1.y + pd4.z * d2.y + pd4.w * d3.y;
            acc[e][2] += pu4.x * u0.z + pu4.y * u1.z + pu4.z * u2.z + pu4.w * u3.z
                       + pd4.x * d0.z + pd4.y * d1.z + pd4.z * d2.z + pd4.w * d3.z;
            acc[e][3] += pu4.x * u0.w + pu4.y * u1.w + pu4.z * u2.w + pu4.w * u3.w
                       + pd4.x * d0.w + pd4.y * d1.w + pd4.z * d2.w + pd4.w * d3.w;
        }
    }

    float* sv_bw = s_v + (size_t)b * 4096;
    float msum[4] = {0.f, 0.f, 0.f, 0.f};
#pragma unroll
    for (int e = 0; e < 8; ++e) {
        float v[4];
#pragma unroll
        for (int jj = 0; jj < 4; ++jj) {
            v[jj] = fast_tanh(acc[e][jj] + sh[c0 + jj]);
            if (residual) v[jj] += sOld[e0 + e][c0 + jj];
            msum[jj] += v[jj];
        }
        *(float4*)&sv_bw[(e0 + e) * 256 + c0] = make_float4(v[0], v[1], v[2], v[3]);
    }
    if (write_means) {
        // half 0 electrons -> mu (smean row 0); half 1 -> md (row 1)
        float* smw = smean + (size_t)b * 512 + half * 256;
        *(float4*)&smw[c0] = make_float4(msum[0] * 0.125f, msum[1] * 0.125f,
                                         msum[2] * 0.125f, msum[3] * 0.125f);
    }
}

// ---------------------------------------------------------------------------
// Orbitals: sw = s_final[:,spin] @ W + b, * env; write orb (B,2,16(det),8(j),8(i))
// ---------------------------------------------------------------------------
__global__ __launch_bounds__(256) void k_orb(
    const float* __restrict__ r, const float* __restrict__ a,
    const float* __restrict__ s_v,
    const float* __restrict__ wuW, const float* __restrict__ wub,
    const float* __restrict__ wdW, const float* __restrict__ wdb,
    float* __restrict__ orb)
{
    const int b   = blockIdx.x;
    const int tid = threadIdx.x;
    __shared__ float sF[16][256];
    __shared__ float envl[16];
    const float* sv_b = s_v + (size_t)b * 4096;
    float* sFF = &sF[0][0];
    for (int t = tid * 4; t < 4096; t += 1024)
        *(float4*)&sFF[t] = *(const float4*)&sv_b[t];
    if (tid < 16) {
        float ex = 0.f;
#pragma unroll
        for (int at = 0; at < 4; ++at) {
            float dx = r[b * 48 + tid * 3 + 0] - a[at * 3 + 0];
            float dy = r[b * 48 + tid * 3 + 1] - a[at * 3 + 1];
            float dz = r[b * 48 + tid * 3 + 2] - a[at * 3 + 2];
            ex += __expf(-sqrtf(dx * dx + dy * dy + dz * dz));
        }
        envl[tid] = ex;
    }
    __syncthreads();

    const int spin = tid >> 7;
    const int c    = tid & 127;
    const float* Wm = spin ? wdW : wuW;
    const float* bm = spin ? wdb : wub;
    const int e0 = spin * 8;
    float acc[8];
    const float bias = bm[c];
#pragma unroll
    for (int e = 0; e < 8; ++e) acc[e] = bias;
    for (int k = 0; k < 256; k += 4) {
        float w0 = Wm[(k + 0) * 128 + c];
        float w1 = Wm[(k + 1) * 128 + c];
        float w2 = Wm[(k + 2) * 128 + c];
        float w3 = Wm[(k + 3) * 128 + c];
#pragma unroll
        for (int e = 0; e < 8; ++e) {
            float4 s4 = *(const float4*)&sF[e0 + e][k];
            acc[e] += s4.x * w0 + s4.y * w1 + s4.z * w2 + s4.w * w3;
        }
    }
    const int d = c & 15, jrow = c >> 4;
    float out[8];
#pragma unroll
    for (int e = 0; e < 8; ++e) out[e] = acc[e] * envl[e0 + e];
    float* dst = orb + ((size_t)((b * 2 + spin) * 16 + d) * 8 + jrow) * 8;
    *(float4*)dst       = make_float4(out[0], out[1], out[2], out[3]);
    *(float4*)(dst + 4) = make_float4(out[4], out[5], out[6], out[7]);
}

// ---------------------------------------------------------------------------
// slogdet of 8x8 (partial pivoting, fully unrolled) + det-combine + logsumexp
// ---------------------------------------------------------------------------
__device__ __forceinline__ void slogdet8(float M[8][8], float& sgn_out, float& ld_out) {
    float sgn = 1.f, ld = 0.f;
#pragma unroll
    for (int k = 0; k < 8; ++k) {
        float best = fabsf(M[k][k]);
        int p = k;
#pragma unroll
        for (int rr = k + 1; rr < 8; ++rr) {
            float v = fabsf(M[rr][k]);
            if (v > best) { best = v; p = rr; }
        }
        if (p != k) sgn = -sgn;
#pragma unroll
        for (int rr = k + 1; rr < 8; ++rr) {
            bool sw = (rr == p);
#pragma unroll
            for (int cc = k; cc < 8; ++cc) {
                float x = M[k][cc], y = M[rr][cc];
                M[k][cc]  = sw ? y : x;
                M[rr][cc] = sw ? x : y;
            }
        }
        float piv = M[k][k];
        if (piv < 0.f) sgn = -sgn;
        ld += logf(fabsf(piv));
        float inv = 1.f / piv;
#pragma unroll
        for (int rr = k + 1; rr < 8; ++rr) {
            float f = M[rr][k] * inv;
#pragma unroll
            for (int cc = k + 1; cc < 8; ++cc) M[rr][cc] -= f * M[k][cc];
        }
    }
    sgn_out = sgn; ld_out = ld;
}

__global__ __launch_bounds__(256) void k_det(
    const float* __restrict__ orb, const float* __restrict__ wfW,
    float* __restrict__ out)
{
    const int g = blockIdx.x * 256 + threadIdx.x;
    const int b = g >> 4, d = g & 15;
    float M[8][8];
    const float* src = orb + (size_t)((b * 2 + 0) * 16 + d) * 64;
#pragma unroll
    for (int rr = 0; rr < 8; ++rr) {
        float4 v0 = *(const float4*)&src[rr * 8];
        float4 v1 = *(const float4*)&src[rr * 8 + 4];
        M[rr][0] = v0.x; M[rr][1] = v0.y; M[rr][2] = v0.z; M[rr][3] = v0.w;
        M[rr][4] = v1.x; M[rr][5] = v1.y; M[rr][6] = v1.z; M[rr][7] = v1.w;
    }
    float s1, l1; slogdet8(M, s1, l1);
    src = orb + (size_t)((b * 2 + 1) * 16 + d) * 64;
#pragma unroll
    for (int rr = 0; rr < 8; ++rr) {
        float4 v0 = *(const float4*)&src[rr * 8];
        float4 v1 = *(const float4*)&src[rr * 8 + 4];
        M[rr][0] = v0.x; M[rr][1] = v0.y; M[rr][2] = v0.z; M[rr][3] = v0.w;
        M[rr][4] = v1.x; M[rr][5] = v1.y; M[rr][6] = v1.z; M[rr][7] = v1.w;
    }
    float s2, l2; slogdet8(M, s2, l2);
    float sgn = s1 * s2;
    float ld  = l1 + l2;

    float m = ld;
    m = fmaxf(m, __shfl_xor(m, 1));
    m = fmaxf(m, __shfl_xor(m, 2));
    m = fmaxf(m, __shfl_xor(m, 4));
    m = fmaxf(m, __shfl_xor(m, 8));
    float sub = sgn * __expf(ld - m) * wfW[d];
    sub += __shfl_xor(sub, 1);
    sub += __shfl_xor(sub, 2);
    sub += __shfl_xor(sub, 4);
    sub += __shfl_xor(sub, 8);
    if (d == 0) out[b] = logf(fabsf(sub)) + m;
}

// ---------------------------------------------------------------------------
extern "C" void kernel_launch(void* const* d_in, const int* in_sizes, int n_in,
                              void* d_out, int out_size, void* d_ws, size_t ws_size,
                              hipStream_t stream) {
    (void)in_sizes; (void)n_in; (void)out_size; (void)ws_size;
    const float* r   = (const float*)d_in[0];
    const float* a   = (const float*)d_in[1];
    const float* sW0 = (const float*)d_in[2];
    const float* sb0 = (const float*)d_in[3];
    const float* sW  = (const float*)d_in[4];
    const float* sb  = (const float*)d_in[5];
    const float* pW0 = (const float*)d_in[6];
    const float* pb0 = (const float*)d_in[7];
    const float* pW  = (const float*)d_in[8];
    const float* pb  = (const float*)d_in[9];
    const float* vW  = (const float*)d_in[10];
    const float* vb  = (const float*)d_in[11];
    const float* wuW = (const float*)d_in[12];
    const float* wub = (const float*)d_in[13];
    const float* wdW = (const float*)d_in[14];
    const float* wdb = (const float*)d_in[15];
    const float* wfW = (const float*)d_in[16];
    float* out = (float*)d_out;

    float* ws     = (float*)d_ws;
    float* pmeans = ws;                          // 5 * 2,097,152 = 10,485,760 floats
    float* s_v    = ws + (size_t)5 * STAGE_SZ;   // 8,388,608 floats
    float* smean  = s_v + (size_t)NB * 4096;     // 1,048,576 floats
    float* orb    = pmeans;                      // alias: stages 0-1 dead by k_orb time

    k_pstream<<<NB, 256, 0, stream>>>(r, pW0, pb0, pW, pb, pmeans);
    k_s0<<<NB, 256, 0, stream>>>(r, a, sW0, sb0, s_v, smean);
    for (int l = 0; l < 4; ++l) {
        k_slayer<<<NB, 128, 0, stream>>>(sW + (size_t)l * 832 * 256, sb + l * 256,
                                         pmeans + (size_t)l * STAGE_SZ,
                                         s_v, smean, 1, 1);
    }
    k_slayer<<<NB, 128, 0, stream>>>(vW, vb, pmeans + (size_t)4 * STAGE_SZ,
                                     s_v, smean, 0, 0);
    k_orb<<<NB, 256, 0, stream>>>(r, a, s_v, wuW, wub, wdW, wdb, orb);
    k_det<<<NB / 16, 256, 0, stream>>>(orb, wfW, out);
}

// Round 3
// 1695.326 us; speedup vs baseline: 1.1656x; 1.1656x over previous
//
#include <hip/hip_runtime.h>
#include <math.h>

#define NB 2048
#define STAGE_SZ (NB * 16 * 2 * 32)  // 2,097,152 floats per p-mean stage

__device__ __forceinline__ float fast_tanh(float x) {
    float ax = fabsf(x);
    float e  = __expf(2.0f * ax);
    float t  = 1.0f - 2.0f / (e + 1.0f);
    return copysignf(t, x);
}

// ---------------------------------------------------------------------------
// p-stream, LDS-state design (R2 post-mortem: compiler demotes >=32-float
// per-thread arrays to accvgpr/scratch regardless of launch bounds -> 15x
// VALU bloat. So: pair state lives in LDS transposed pst[feat][pair],
// thread = (pair, k-half) holds only acc[16]+pcur[16] in VGPRs).
// Block = 1 walker = 512 threads (8 waves): wave = (pairgroup<<1)|chunk.
// Weights are wave-uniform (k-chunk scalarized) -> s_load, FMA w/ SGPR src.
// pmeans layout: (5, B, 16(j), 2(h), 32)
// ---------------------------------------------------------------------------
__global__ __launch_bounds__(512, 4) void k_pstream(
    const float* __restrict__ r,
    const float* __restrict__ pW0, const float* __restrict__ pb0,
    const float* __restrict__ pW,  const float* __restrict__ pb,
    float* __restrict__ pmeans)
{
    const int b    = blockIdx.x;
    const int tid  = threadIdx.x;
    const int lane = tid & 63;
    const int wv   = __builtin_amdgcn_readfirstlane(tid >> 6);  // wave-uniform
    const int pg   = wv >> 1;      // pair group: 64 pairs each
    const int k0   = (wv & 1) * 16; // this thread's output-feature chunk
    const int pair = pg * 64 + lane;
    const int i    = pair >> 4;    // reduced index (axis 1 of p_v)
    const int j    = pair & 15;    // kept index

    __shared__ float rl[48];
    __shared__ float pst[32][257]; // [feat][pair], pad -> conflict-free

    if (tid < 48) rl[tid] = r[b * 48 + tid];
    __syncthreads();

    // rr[b,i,j] = r[b,j] - r[b,i]; eye adds 1 per component on diagonal (len only)
    const float dx = rl[j * 3 + 0] - rl[i * 3 + 0];
    const float dy = rl[j * 3 + 1] - rl[i * 3 + 1];
    const float dz = rl[j * 3 + 2] - rl[i * 3 + 2];
    const float ee = (i == j) ? 1.0f : 0.0f;
    const float len = sqrtf((dx + ee) * (dx + ee) + (dy + ee) * (dy + ee) + (dz + ee) * (dz + ee));

    float pcur[16];
    // ---- layer 0: p = tanh(in4 @ pW0 + pb0)
    {
#pragma unroll
        for (int kk = 0; kk < 16; ++kk) {
            const int k = k0 + kk;
            float acc = pb0[k];
            acc += dx  * pW0[0 * 32 + k];
            acc += dy  * pW0[1 * 32 + k];
            acc += dz  * pW0[2 * 32 + k];
            acc += len * pW0[3 * 32 + k];
            pcur[kk] = fast_tanh(acc);
            pst[k][pair] = pcur[kk];
        }
    }
    __syncthreads();

    // ---- stage-0 means: out o = j*64 + h*32 + k, 1024 per walker
#pragma unroll
    for (int rep = 0; rep < 2; ++rep) {
        const int o  = tid + rep * 512;
        const int mj = o >> 6, mh = (o >> 5) & 1, mk = o & 31;
        float s = 0.f;
#pragma unroll
        for (int i8 = 0; i8 < 8; ++i8) s += pst[mk][(mh * 8 + i8) * 16 + mj];
        pmeans[(size_t)0 * STAGE_SZ + (size_t)b * 1024 + o] = s * 0.125f;
    }

    // ---- residual layers 1..4
    for (int l = 0; l < 4; ++l) {
        const float* __restrict__ Wl = pW + l * 1024 + k0;  // uniform base
        const float* __restrict__ bl = pb + l * 32 + k0;
        float acc[16];
#pragma unroll
        for (int kk = 0; kk < 16; ++kk) acc[kk] = bl[kk];
#pragma unroll
        for (int m = 0; m < 32; ++m) {
            const float f = pst[m][pair];
            const float* wrow = Wl + m * 32;   // wave-uniform -> s_load
#pragma unroll
            for (int kk = 0; kk < 16; ++kk) acc[kk] += f * wrow[kk];
        }
        __syncthreads();   // all reads of current pst done (incl. means above)
#pragma unroll
        for (int kk = 0; kk < 16; ++kk) {
            pcur[kk] = fast_tanh(acc[kk]) + pcur[kk];
            pst[k0 + kk][pair] = pcur[kk];
        }
        __syncthreads();   // writes visible
        // stage (l+1) means
#pragma unroll
        for (int rep = 0; rep < 2; ++rep) {
            const int o  = tid + rep * 512;
            const int mj = o >> 6, mh = (o >> 5) & 1, mk = o & 31;
            float s = 0.f;
#pragma unroll
            for (int i8 = 0; i8 < 8; ++i8) s += pst[mk][(mh * 8 + i8) * 16 + mj];
            pmeans[(size_t)(l + 1) * STAGE_SZ + (size_t)b * 1024 + o] = s * 0.125f;
        }
    }
}

// ---------------------------------------------------------------------------
// Layer 0: build s_emb / p_emb means in-block, blk0 (16x56), s_v1 = tanh(blk0@sW0+sb0)
// writes s_v (B,16,256) and smean (B,2,256)
// ---------------------------------------------------------------------------
__global__ __launch_bounds__(256) void k_s0(
    const float* __restrict__ r, const float* __restrict__ a,
    const float* __restrict__ sW0, const float* __restrict__ sb0,
    float* __restrict__ s_v, float* __restrict__ smean)
{
    const int b   = blockIdx.x;
    const int tid = threadIdx.x;
    __shared__ float rl[48];
    __shared__ float al[12];
    __shared__ float pin[16][16][4];  // [j][i][4] = p_v[b,i,j,:]
    __shared__ float se[16][16];      // s_emb
    __shared__ float sm0[2][16];
    __shared__ float pm0[16][2][4];
    __shared__ float blk[16][56];

    if (tid < 48) rl[tid] = r[b * 48 + tid];
    if (tid >= 64 && tid < 76) al[tid - 64] = a[tid - 64];
    __syncthreads();
    {
        const int i = tid & 15, j = tid >> 4;
        float dx = rl[j * 3 + 0] - rl[i * 3 + 0];
        float dy = rl[j * 3 + 1] - rl[i * 3 + 1];
        float dz = rl[j * 3 + 2] - rl[i * 3 + 2];
        float ee = (i == j) ? 1.0f : 0.0f;
        float len = sqrtf((dx + ee) * (dx + ee) + (dy + ee) * (dy + ee) + (dz + ee) * (dz + ee));
        pin[j][i][0] = dx; pin[j][i][1] = dy; pin[j][i][2] = dz; pin[j][i][3] = len;
    }
    if (tid < 16) {
        const int e = tid;
#pragma unroll
        for (int at = 0; at < 4; ++at) {
            float dx = rl[e * 3 + 0] - al[at * 3 + 0];
            float dy = rl[e * 3 + 1] - al[at * 3 + 1];
            float dz = rl[e * 3 + 2] - al[at * 3 + 2];
            float ln = sqrtf(dx * dx + dy * dy + dz * dz);
            se[e][at * 4 + 0] = dx; se[e][at * 4 + 1] = dy;
            se[e][at * 4 + 2] = dz; se[e][at * 4 + 3] = ln;
        }
    }
    __syncthreads();
    if (tid < 32) {
        const int h = tid >> 4, f = tid & 15;
        float s = 0.f;
        for (int e = 0; e < 8; ++e) s += se[h * 8 + e][f];
        sm0[h][f] = s * 0.125f;
    }
    if (tid < 128) {
        const int j = tid >> 3, h = (tid >> 2) & 1, f = tid & 3;
        float s = 0.f;
        for (int i2 = 0; i2 < 8; ++i2) s += pin[j][h * 8 + i2][f];
        pm0[j][h][f] = s * 0.125f;
    }
    __syncthreads();
    for (int t = tid; t < 16 * 56; t += 256) {
        const int e = t / 56, k = t % 56;
        float v;
        if (k < 16)      v = se[e][k];
        else if (k < 32) v = sm0[0][k - 16];
        else if (k < 48) v = sm0[1][k - 32];
        else if (k < 52) v = pm0[e][0][k - 48];
        else             v = pm0[e][1][k - 52];
        blk[e][k] = v;
    }
    __syncthreads();

    const int n = tid;
    float acc[16];
#pragma unroll
    for (int e = 0; e < 16; ++e) acc[e] = sb0[n];
    for (int k = 0; k < 56; k += 4) {
        float w0 = sW0[(k + 0) * 256 + n];
        float w1 = sW0[(k + 1) * 256 + n];
        float w2 = sW0[(k + 2) * 256 + n];
        float w3 = sW0[(k + 3) * 256 + n];
#pragma unroll
        for (int e = 0; e < 16; ++e) {
            float4 s4 = *(const float4*)&blk[e][k];
            acc[e] += s4.x * w0 + s4.y * w1 + s4.z * w2 + s4.w * w3;
        }
    }
    float* sv_b = s_v + (size_t)b * 4096;
    float mu = 0.f, md = 0.f;
#pragma unroll
    for (int e = 0; e < 16; ++e) {
        float v = fast_tanh(acc[e]);
        sv_b[e * 256 + n] = v;
        if (e < 8) mu += v; else md += v;
    }
    smean[(size_t)b * 512 + n]       = mu * 0.125f;
    smean[(size_t)b * 512 + 256 + n] = md * 0.125f;
}

// ---------------------------------------------------------------------------
// Residual / output s-layer. Decomposed blk @ W:
//   W rows [0,256)=s, [256,512)=mu, [512,768)=md, [768,800)=pu, [800,832)=pd
// block = 1 walker, 128 threads.
// Phase 0: thread t computes row-constant sh[c] for c = 2t, 2t+1 -> LDS.
// Phase 1: thread = (electron-half, 4 cols).
// ---------------------------------------------------------------------------
__global__ __launch_bounds__(128, 2) void k_slayer(
    const float* __restrict__ W, const float* __restrict__ bias,
    const float* __restrict__ pstage,  // (B,16,2,32) for this layer
    float* __restrict__ s_v, float* __restrict__ smean,
    int residual, int write_means)
{
    const int b   = blockIdx.x;
    const int tid = threadIdx.x;
    __shared__ float sOld[16][256];
    __shared__ float mumd[2][256];
    __shared__ float pupd[16][2][32];
    __shared__ float sh[256];

    const float* sv_b = s_v + (size_t)b * 4096;
    const float* sm_b = smean + (size_t)b * 512;
    const float* ps_b = pstage + (size_t)b * 1024;

    float* sOldF = &sOld[0][0];
    float* mumdF = &mumd[0][0];
    float* pupdF = &pupd[0][0][0];
    for (int t = tid * 4; t < 4096; t += 512)
        *(float4*)&sOldF[t] = *(const float4*)&sv_b[t];
    {
        int t = tid * 4;
        *(float4*)&mumdF[t] = *(const float4*)&sm_b[t];
    }
    for (int t = tid * 4; t < 1024; t += 512)
        *(float4*)&pupdF[t] = *(const float4*)&ps_b[t];
    __syncthreads();

    // ---- phase 0: row-constant part sh[c] = bias + mu@W[256:512] + md@W[512:768]
    {
        const int n0 = tid * 2;
        float sh0 = bias[n0], sh1 = bias[n0 + 1];
        for (int k = 0; k < 256; k += 4) {
            float4 mu4 = *(const float4*)&mumd[0][k];
            float4 md4 = *(const float4*)&mumd[1][k];
            float2 a0 = *(const float2*)&W[(256 + k + 0) * 256 + n0];
            float2 a1 = *(const float2*)&W[(256 + k + 1) * 256 + n0];
            float2 a2 = *(const float2*)&W[(256 + k + 2) * 256 + n0];
            float2 a3 = *(const float2*)&W[(256 + k + 3) * 256 + n0];
            float2 c0 = *(const float2*)&W[(512 + k + 0) * 256 + n0];
            float2 c1 = *(const float2*)&W[(512 + k + 1) * 256 + n0];
            float2 c2 = *(const float2*)&W[(512 + k + 2) * 256 + n0];
            float2 c3 = *(const float2*)&W[(512 + k + 3) * 256 + n0];
            sh0 += mu4.x * a0.x + mu4.y * a1.x + mu4.z * a2.x + mu4.w * a3.x
                 + md4.x * c0.x + md4.y * c1.x + md4.z * c2.x + md4.w * c3.x;
            sh1 += mu4.x * a0.y + mu4.y * a1.y + mu4.z * a2.y + mu4.w * a3.y
                 + md4.x * c0.y + md4.y * c1.y + md4.z * c2.y + md4.w * c3.y;
        }
        sh[n0] = sh0; sh[n0 + 1] = sh1;
    }
    __syncthreads();

    // ---- phase 1: 8 electrons x 4 cols per thread
    const int half = tid >> 6;        // 0: e 0-7, 1: e 8-15
    const int e0   = half * 8;
    const int c0   = (tid & 63) * 4;

    float acc[8][4];
#pragma unroll
    for (int e = 0; e < 8; ++e)
#pragma unroll
        for (int jj = 0; jj < 4; ++jj) acc[e][jj] = 0.f;

    // s part: W rows [0,256)
    for (int k = 0; k < 256; k += 4) {
        float4 w0 = *(const float4*)&W[(k + 0) * 256 + c0];
        float4 w1 = *(const float4*)&W[(k + 1) * 256 + c0];
        float4 w2 = *(const float4*)&W[(k + 2) * 256 + c0];
        float4 w3 = *(const float4*)&W[(k + 3) * 256 + c0];
#pragma unroll
        for (int e = 0; e < 8; ++e) {
            float4 s4 = *(const float4*)&sOld[e0 + e][k];
            acc[e][0] += s4.x * w0.x + s4.y * w1.x + s4.z * w2.x + s4.w * w3.x;
            acc[e][1] += s4.x * w0.y + s4.y * w1.y + s4.z * w2.y + s4.w * w3.y;
            acc[e][2] += s4.x * w0.z + s4.y * w1.z + s4.z * w2.z + s4.w * w3.z;
            acc[e][3] += s4.x * w0.w + s4.y * w1.w + s4.z * w2.w + s4.w * w3.w;
        }
    }
    // p part: rows [768,832)
    for (int k = 0; k < 32; k += 4) {
        float4 u0 = *(const float4*)&W[(768 + k + 0) * 256 + c0];
        float4 u1 = *(const float4*)&W[(768 + k + 1) * 256 + c0];
        float4 u2 = *(const float4*)&W[(768 + k + 2) * 256 + c0];
        float4 u3 = *(const float4*)&W[(768 + k + 3) * 256 + c0];
        float4 d0 = *(const float4*)&W[(800 + k + 0) * 256 + c0];
        float4 d1 = *(const float4*)&W[(800 + k + 1) * 256 + c0];
        float4 d2 = *(const float4*)&W[(800 + k + 2) * 256 + c0];
        float4 d3 = *(const float4*)&W[(800 + k + 3) * 256 + c0];
#pragma unroll
        for (int e = 0; e < 8; ++e) {
            float4 pu4 = *(const float4*)&pupd[e0 + e][0][k];
            float4 pd4 = *(const float4*)&pupd[e0 + e][1][k];
            acc[e][0] += pu4.x * u0.x + pu4.y * u1.x + pu4.z * u2.x + pu4.w * u3.x
                       + pd4.x * d0.x + pd4.y * d1.x + pd4.z * d2.x + pd4.w * d3.x;
            acc[e][1] += pu4.x * u0.y + pu4.y * u1.y + pu4.z * u2.y + pu4.w * u3.y
                       + pd4.x * d0.y + pd4.y * d1.y + pd4.z * d2.y + pd4.w * d3.y;
            acc[e][2] += pu4.x * u0.z + pu4.y * u1.z + pu4.z * u2.z + pu4.w * u3.z
                       + pd4.x * d0.z + pd4.y * d1.z + pd4.z * d2.z + pd4.w * d3.z;
            acc[e][3] += pu4.x * u0.w + pu4.y * u1.w + pu4.z * u2.w + pu4.w * u3.w
                       + pd4.x * d0.w + pd4.y * d1.w + pd4.z * d2.w + pd4.w * d3.w;
        }
    }

    float* sv_bw = s_v + (size_t)b * 4096;
    float msum[4] = {0.f, 0.f, 0.f, 0.f};
#pragma unroll
    for (int e = 0; e < 8; ++e) {
        float v[4];
#pragma unroll
        for (int jj = 0; jj < 4; ++jj) {
            v[jj] = fast_tanh(acc[e][jj] + sh[c0 + jj]);
            if (residual) v[jj] += sOld[e0 + e][c0 + jj];
            msum[jj] += v[jj];
        }
        *(float4*)&sv_bw[(e0 + e) * 256 + c0] = make_float4(v[0], v[1], v[2], v[3]);
    }
    if (write_means) {
        // half 0 electrons -> mu (smean row 0); half 1 -> md (row 1)
        float* smw = smean + (size_t)b * 512 + half * 256;
        *(float4*)&smw[c0] = make_float4(msum[0] * 0.125f, msum[1] * 0.125f,
                                         msum[2] * 0.125f, msum[3] * 0.125f);
    }
}

// ---------------------------------------------------------------------------
// Orbitals: sw = s_final[:,spin] @ W + b, * env; write orb (B,2,16(det),8(j),8(i))
// ---------------------------------------------------------------------------
__global__ __launch_bounds__(256) void k_orb(
    const float* __restrict__ r, const float* __restrict__ a,
    const float* __restrict__ s_v,
    const float* __restrict__ wuW, const float* __restrict__ wub,
    const float* __restrict__ wdW, const float* __restrict__ wdb,
    float* __restrict__ orb)
{
    const int b   = blockIdx.x;
    const int tid = threadIdx.x;
    __shared__ float sF[16][256];
    __shared__ float envl[16];
    const float* sv_b = s_v + (size_t)b * 4096;
    float* sFF = &sF[0][0];
    for (int t = tid * 4; t < 4096; t += 1024)
        *(float4*)&sFF[t] = *(const float4*)&sv_b[t];
    if (tid < 16) {
        float ex = 0.f;
#pragma unroll
        for (int at = 0; at < 4; ++at) {
            float dx = r[b * 48 + tid * 3 + 0] - a[at * 3 + 0];
            float dy = r[b * 48 + tid * 3 + 1] - a[at * 3 + 1];
            float dz = r[b * 48 + tid * 3 + 2] - a[at * 3 + 2];
            ex += __expf(-sqrtf(dx * dx + dy * dy + dz * dz));
        }
        envl[tid] = ex;
    }
    __syncthreads();

    const int spin = tid >> 7;
    const int c    = tid & 127;
    const float* Wm = spin ? wdW : wuW;
    const float* bm = spin ? wdb : wub;
    const int e0 = spin * 8;
    float acc[8];
    const float bias = bm[c];
#pragma unroll
    for (int e = 0; e < 8; ++e) acc[e] = bias;
    for (int k = 0; k < 256; k += 4) {
        float w0 = Wm[(k + 0) * 128 + c];
        float w1 = Wm[(k + 1) * 128 + c];
        float w2 = Wm[(k + 2) * 128 + c];
        float w3 = Wm[(k + 3) * 128 + c];
#pragma unroll
        for (int e = 0; e < 8; ++e) {
            float4 s4 = *(const float4*)&sF[e0 + e][k];
            acc[e] += s4.x * w0 + s4.y * w1 + s4.z * w2 + s4.w * w3;
        }
    }
    const int d = c & 15, jrow = c >> 4;
    float out[8];
#pragma unroll
    for (int e = 0; e < 8; ++e) out[e] = acc[e] * envl[e0 + e];
    float* dst = orb + ((size_t)((b * 2 + spin) * 16 + d) * 8 + jrow) * 8;
    *(float4*)dst       = make_float4(out[0], out[1], out[2], out[3]);
    *(float4*)(dst + 4) = make_float4(out[4], out[5], out[6], out[7]);
}

// ---------------------------------------------------------------------------
// slogdet of 8x8 (partial pivoting, fully unrolled) + det-combine + logsumexp
// ---------------------------------------------------------------------------
__device__ __forceinline__ void slogdet8(float M[8][8], float& sgn_out, float& ld_out) {
    float sgn = 1.f, ld = 0.f;
#pragma unroll
    for (int k = 0; k < 8; ++k) {
        float best = fabsf(M[k][k]);
        int p = k;
#pragma unroll
        for (int rr = k + 1; rr < 8; ++rr) {
            float v = fabsf(M[rr][k]);
            if (v > best) { best = v; p = rr; }
        }
        if (p != k) sgn = -sgn;
#pragma unroll
        for (int rr = k + 1; rr < 8; ++rr) {
            bool sw = (rr == p);
#pragma unroll
            for (int cc = k; cc < 8; ++cc) {
                float x = M[k][cc], y = M[rr][cc];
                M[k][cc]  = sw ? y : x;
                M[rr][cc] = sw ? x : y;
            }
        }
        float piv = M[k][k];
        if (piv < 0.f) sgn = -sgn;
        ld += logf(fabsf(piv));
        float inv = 1.f / piv;
#pragma unroll
        for (int rr = k + 1; rr < 8; ++rr) {
            float f = M[rr][k] * inv;
#pragma unroll
            for (int cc = k + 1; cc < 8; ++cc) M[rr][cc] -= f * M[k][cc];
        }
    }
    sgn_out = sgn; ld_out = ld;
}

__global__ __launch_bounds__(256) void k_det(
    const float* __restrict__ orb, const float* __restrict__ wfW,
    float* __restrict__ out)
{
    const int g = blockIdx.x * 256 + threadIdx.x;
    const int b = g >> 4, d = g & 15;
    float M[8][8];
    const float* src = orb + (size_t)((b * 2 + 0) * 16 + d) * 64;
#pragma unroll
    for (int rr = 0; rr < 8; ++rr) {
        float4 v0 = *(const float4*)&src[rr * 8];
        float4 v1 = *(const float4*)&src[rr * 8 + 4];
        M[rr][0] = v0.x; M[rr][1] = v0.y; M[rr][2] = v0.z; M[rr][3] = v0.w;
        M[rr][4] = v1.x; M[rr][5] = v1.y; M[rr][6] = v1.z; M[rr][7] = v1.w;
    }
    float s1, l1; slogdet8(M, s1, l1);
    src = orb + (size_t)((b * 2 + 1) * 16 + d) * 64;
#pragma unroll
    for (int rr = 0; rr < 8; ++rr) {
        float4 v0 = *(const float4*)&src[rr * 8];
        float4 v1 = *(const float4*)&src[rr * 8 + 4];
        M[rr][0] = v0.x; M[rr][1] = v0.y; M[rr][2] = v0.z; M[rr][3] = v0.w;
        M[rr][4] = v1.x; M[rr][5] = v1.y; M[rr][6] = v1.z; M[rr][7] = v1.w;
    }
    float s2, l2; slogdet8(M, s2, l2);
    float sgn = s1 * s2;
    float ld  = l1 + l2;

    float m = ld;
    m = fmaxf(m, __shfl_xor(m, 1));
    m = fmaxf(m, __shfl_xor(m, 2));
    m = fmaxf(m, __shfl_xor(m, 4));
    m = fmaxf(m, __shfl_xor(m, 8));
    float sub = sgn * __expf(ld - m) * wfW[d];
    sub += __shfl_xor(sub, 1);
    sub += __shfl_xor(sub, 2);
    sub += __shfl_xor(sub, 4);
    sub += __shfl_xor(sub, 8);
    if (d == 0) out[b] = logf(fabsf(sub)) + m;
}

// ---------------------------------------------------------------------------
extern "C" void kernel_launch(void* const* d_in, const int* in_sizes, int n_in,
                              void* d_out, int out_size, void* d_ws, size_t ws_size,
                              hipStream_t stream) {
    (void)in_sizes; (void)n_in; (void)out_size; (void)ws_size;
    const float* r   = (const float*)d_in[0];
    const float* a   = (const float*)d_in[1];
    const float* sW0 = (const float*)d_in[2];
    const float* sb0 = (const float*)d_in[3];
    const float* sW  = (const float*)d_in[4];
    const float* sb  = (const float*)d_in[5];
    const float* pW0 = (const float*)d_in[6];
    const float* pb0 = (const float*)d_in[7];
    const float* pW  = (const float*)d_in[8];
    const float* pb  = (const float*)d_in[9];
    const float* vW  = (const float*)d_in[10];
    const float* vb  = (const float*)d_in[11];
    const float* wuW = (const float*)d_in[12];
    const float* wub = (const float*)d_in[13];
    const float* wdW = (const float*)d_in[14];
    const float* wdb = (const float*)d_in[15];
    const float* wfW = (const float*)d_in[16];
    float* out = (float*)d_out;

    float* ws     = (float*)d_ws;
    float* pmeans = ws;                          // 5 * 2,097,152 = 10,485,760 floats
    float* s_v    = ws + (size_t)5 * STAGE_SZ;   // 8,388,608 floats
    float* smean  = s_v + (size_t)NB * 4096;     // 1,048,576 floats
    float* orb    = pmeans;                      // alias: stages 0-1 dead by k_orb time

    k_pstream<<<NB, 512, 0, stream>>>(r, pW0, pb0, pW, pb, pmeans);
    k_s0<<<NB, 256, 0, stream>>>(r, a, sW0, sb0, s_v, smean);
    for (int l = 0; l < 4; ++l) {
        k_slayer<<<NB, 128, 0, stream>>>(sW + (size_t)l * 832 * 256, sb + l * 256,
                                         pmeans + (size_t)l * STAGE_SZ,
                                         s_v, smean, 1, 1);
    }
    k_slayer<<<NB, 128, 0, stream>>>(vW, vb, pmeans + (size_t)4 * STAGE_SZ,
                                     s_v, smean, 0, 0);
    k_orb<<<NB, 256, 0, stream>>>(r, a, s_v, wuW, wub, wdW, wdb, orb);
    k_det<<<NB / 16, 256, 0, stream>>>(orb, wfW, out);
}

// Round 4
// 980.769 us; speedup vs baseline: 2.0147x; 1.7286x over previous
//
#include <hip/hip_runtime.h>
#include <math.h>

#define NB 2048
#define STAGE_SZ (NB * 16 * 2 * 32)  // 2,097,152 floats per p-mean stage

__device__ __forceinline__ float fast_tanh(float x) {
    float ax = fabsf(x);
    float e  = __expf(2.0f * ax);
    float t  = 1.0f - 2.0f / (e + 1.0f);
    return copysignf(t, x);
}

// ---------------------------------------------------------------------------
// p-stream v3. R3 post-mortem: compiler targets LDS-implied max occupancy
// (8 waves/SIMD -> 64-VGPR cap) regardless of launch-bounds min, so per-thread
// state MUST fit in 64 VGPRs. Thread owns 8 features of 1 pair:
// block = 1 walker = 1024 threads = 256 pairs x 4 k-quarters.
// Pair state in LDS transposed pst[feat][pair] (pad 257 -> conflict-free).
// Weights wave-uniform (k0 per wave) -> s_load + FMA-with-SGPR.
// pmeans layout: (5, B, 16(j), 2(h), 32)
// ---------------------------------------------------------------------------
__global__ __launch_bounds__(1024) void k_pstream(
    const float* __restrict__ r,
    const float* __restrict__ pW0, const float* __restrict__ pb0,
    const float* __restrict__ pW,  const float* __restrict__ pb,
    float* __restrict__ pmeans)
{
    const int b    = blockIdx.x;
    const int tid  = threadIdx.x;
    const int lane = tid & 63;
    const int wv   = __builtin_amdgcn_readfirstlane(tid >> 6);  // 0..15, uniform
    const int pg   = wv & 3;          // pair group (64 pairs each)
    const int k0   = (wv >> 2) * 8;   // feature quarter
    const int pair = pg * 64 + lane;
    const int i    = pair >> 4;       // reduced index
    const int j    = pair & 15;       // kept index

    __shared__ float rl[48];
    __shared__ float pst[32][257];

    if (tid < 48) rl[tid] = r[b * 48 + tid];
    __syncthreads();

    const float dx = rl[j * 3 + 0] - rl[i * 3 + 0];
    const float dy = rl[j * 3 + 1] - rl[i * 3 + 1];
    const float dz = rl[j * 3 + 2] - rl[i * 3 + 2];
    const float ee = (i == j) ? 1.0f : 0.0f;
    const float len = sqrtf((dx + ee) * (dx + ee) + (dy + ee) * (dy + ee) + (dz + ee) * (dz + ee));

    float pcur[8];
    // ---- layer 0: p = tanh(in4 @ pW0 + pb0), this thread's 8 features
#pragma unroll
    for (int kk = 0; kk < 8; ++kk) {
        const int k = k0 + kk;
        float acc = pb0[k];
        acc += dx  * pW0[0 * 32 + k];
        acc += dy  * pW0[1 * 32 + k];
        acc += dz  * pW0[2 * 32 + k];
        acc += len * pW0[3 * 32 + k];
        pcur[kk] = fast_tanh(acc);
        pst[k0 + kk][pair] = pcur[kk];
    }
    __syncthreads();

    // ---- stage-0 means: o = j*64 + h*32 + k (1024 outputs, 1 per thread)
    {
        const int o  = tid;
        const int mj = o >> 6, mh = (o >> 5) & 1, mk = o & 31;
        float s = 0.f;
#pragma unroll
        for (int i8 = 0; i8 < 8; ++i8) s += pst[mk][(mh * 8 + i8) * 16 + mj];
        pmeans[(size_t)b * 1024 + o] = s * 0.125f;
    }

    // ---- residual layers 1..4
    for (int l = 0; l < 4; ++l) {
        const float* __restrict__ Wl = pW + l * 1024;
        float acc[8];
#pragma unroll
        for (int kk = 0; kk < 8; ++kk) acc[kk] = pb[l * 32 + k0 + kk];
#pragma unroll
        for (int m = 0; m < 32; ++m) {
            const float f = pst[m][pair];
            const float* wrow = Wl + m * 32 + k0;   // wave-uniform -> s_load
#pragma unroll
            for (int kk = 0; kk < 8; ++kk) acc[kk] += f * wrow[kk];
        }
        __syncthreads();   // all reads of current pst done (matvec + prior means)
#pragma unroll
        for (int kk = 0; kk < 8; ++kk) {
            pcur[kk] = fast_tanh(acc[kk]) + pcur[kk];
            pst[k0 + kk][pair] = pcur[kk];
        }
        __syncthreads();   // writes visible
        {
            const int o  = tid;
            const int mj = o >> 6, mh = (o >> 5) & 1, mk = o & 31;
            float s = 0.f;
#pragma unroll
            for (int i8 = 0; i8 < 8; ++i8) s += pst[mk][(mh * 8 + i8) * 16 + mj];
            pmeans[(size_t)(l + 1) * STAGE_SZ + (size_t)b * 1024 + o] = s * 0.125f;
        }
    }
}

// ---------------------------------------------------------------------------
// Layer 0: build s_emb / p_emb means in-block, blk0 (16x56), s_v1 = tanh(blk0@sW0+sb0)
// writes s_v (B,16,256) and smean (B,2,256)
// ---------------------------------------------------------------------------
__global__ __launch_bounds__(256) void k_s0(
    const float* __restrict__ r, const float* __restrict__ a,
    const float* __restrict__ sW0, const float* __restrict__ sb0,
    float* __restrict__ s_v, float* __restrict__ smean)
{
    const int b   = blockIdx.x;
    const int tid = threadIdx.x;
    __shared__ float rl[48];
    __shared__ float al[12];
    __shared__ float pin[16][16][4];  // [j][i][4] = p_v[b,i,j,:]
    __shared__ float se[16][16];      // s_emb
    __shared__ float sm0[2][16];
    __shared__ float pm0[16][2][4];
    __shared__ float blk[16][56];

    if (tid < 48) rl[tid] = r[b * 48 + tid];
    if (tid >= 64 && tid < 76) al[tid - 64] = a[tid - 64];
    __syncthreads();
    {
        const int i = tid & 15, j = tid >> 4;
        float dx = rl[j * 3 + 0] - rl[i * 3 + 0];
        float dy = rl[j * 3 + 1] - rl[i * 3 + 1];
        float dz = rl[j * 3 + 2] - rl[i * 3 + 2];
        float ee = (i == j) ? 1.0f : 0.0f;
        float len = sqrtf((dx + ee) * (dx + ee) + (dy + ee) * (dy + ee) + (dz + ee) * (dz + ee));
        pin[j][i][0] = dx; pin[j][i][1] = dy; pin[j][i][2] = dz; pin[j][i][3] = len;
    }
    if (tid < 16) {
        const int e = tid;
#pragma unroll
        for (int at = 0; at < 4; ++at) {
            float dx = rl[e * 3 + 0] - al[at * 3 + 0];
            float dy = rl[e * 3 + 1] - al[at * 3 + 1];
            float dz = rl[e * 3 + 2] - al[at * 3 + 2];
            float ln = sqrtf(dx * dx + dy * dy + dz * dz);
            se[e][at * 4 + 0] = dx; se[e][at * 4 + 1] = dy;
            se[e][at * 4 + 2] = dz; se[e][at * 4 + 3] = ln;
        }
    }
    __syncthreads();
    if (tid < 32) {
        const int h = tid >> 4, f = tid & 15;
        float s = 0.f;
        for (int e = 0; e < 8; ++e) s += se[h * 8 + e][f];
        sm0[h][f] = s * 0.125f;
    }
    if (tid < 128) {
        const int j = tid >> 3, h = (tid >> 2) & 1, f = tid & 3;
        float s = 0.f;
        for (int i2 = 0; i2 < 8; ++i2) s += pin[j][h * 8 + i2][f];
        pm0[j][h][f] = s * 0.125f;
    }
    __syncthreads();
    for (int t = tid; t < 16 * 56; t += 256) {
        const int e = t / 56, k = t % 56;
        float v;
        if (k < 16)      v = se[e][k];
        else if (k < 32) v = sm0[0][k - 16];
        else if (k < 48) v = sm0[1][k - 32];
        else if (k < 52) v = pm0[e][0][k - 48];
        else             v = pm0[e][1][k - 52];
        blk[e][k] = v;
    }
    __syncthreads();

    const int n = tid;
    float acc[16];
#pragma unroll
    for (int e = 0; e < 16; ++e) acc[e] = sb0[n];
    for (int k = 0; k < 56; k += 4) {
        float w0 = sW0[(k + 0) * 256 + n];
        float w1 = sW0[(k + 1) * 256 + n];
        float w2 = sW0[(k + 2) * 256 + n];
        float w3 = sW0[(k + 3) * 256 + n];
#pragma unroll
        for (int e = 0; e < 16; ++e) {
            float4 s4 = *(const float4*)&blk[e][k];
            acc[e] += s4.x * w0 + s4.y * w1 + s4.z * w2 + s4.w * w3;
        }
    }
    float* sv_b = s_v + (size_t)b * 4096;
    float mu = 0.f, md = 0.f;
#pragma unroll
    for (int e = 0; e < 16; ++e) {
        float v = fast_tanh(acc[e]);
        sv_b[e * 256 + n] = v;
        if (e < 8) mu += v; else md += v;
    }
    smean[(size_t)b * 512 + n]       = mu * 0.125f;
    smean[(size_t)b * 512 + 256 + n] = md * 0.125f;
}

// ---------------------------------------------------------------------------
// Residual / output s-layer v2. Decomposed blk @ W:
//   W rows [0,256)=s, [256,512)=mu, [512,768)=md, [768,832)=pu|pd
// Block = 2 walkers, 256 threads (4 waves). All 4 waves stream the SAME
// phase-1 weight addresses -> L1 dedup halves L2 traffic vs 1-walker blocks.
// k-loop unrolled x8 with batched b128 loads for memory-level parallelism.
// ---------------------------------------------------------------------------
__global__ __launch_bounds__(256, 3) void k_slayer(
    const float* __restrict__ W, const float* __restrict__ bias,
    const float* __restrict__ pstage,  // (B,16,2,32) for this layer
    float* __restrict__ s_v, float* __restrict__ smean,
    int residual, int write_means)
{
    const int b2  = blockIdx.x;   // walker pair
    const int tid = threadIdx.x;
    __shared__ float sOld[2][16][256];  // 32 KB
    __shared__ float pupd[2][16][64];   // 8 KB ([e][q], q = W-row - 768)
    __shared__ float mumd[2][2][256];   // 4 KB
    __shared__ float sh[2][256];        // 2 KB

    // cooperative loads (both walkers)
    {
        float* sOldF = &sOld[0][0][0];
        const float* src = s_v + (size_t)b2 * 8192;
        for (int t = tid * 4; t < 8192; t += 1024)
            *(float4*)&sOldF[t] = *(const float4*)&src[t];
        float* mumdF = &mumd[0][0][0];
        const float* sm = smean + (size_t)b2 * 1024;
        for (int t = tid * 4; t < 1024; t += 1024)
            *(float4*)&mumdF[t] = *(const float4*)&sm[t];
        // second quarter of mumd
        {
            int t = tid * 4;
            if (t < 1024) { /* covered above */ }
        }
        for (int t = tid * 4; t < 1024; t += 1024)
            ;  // no-op placeholder
        // full 1024 floats of mumd: 256 threads x float4 = 1024 exactly
        // (loop above runs once; kept explicit below for clarity)
        float* pupdF = &pupd[0][0][0];
        const float* ps = pstage + (size_t)b2 * 2048;
        for (int t = tid * 4; t < 2048; t += 1024)
            *(float4*)&pupdF[t] = *(const float4*)&ps[t];
    }
    __syncthreads();

    // ---- phase 0: sh[w][c] = bias[c] + mu.W[256:512][:,c] + md.W[512:768][:,c]
    {
        const int w_ = tid >> 7;
        const int n0 = (tid & 127) * 2;
        float sh0 = bias[n0], sh1 = bias[n0 + 1];
#pragma unroll 2
        for (int k = 0; k < 256; k += 4) {
            float4 mu4 = *(const float4*)&mumd[w_][0][k];
            float4 md4 = *(const float4*)&mumd[w_][1][k];
            float2 a0 = *(const float2*)&W[(256 + k + 0) * 256 + n0];
            float2 a1 = *(const float2*)&W[(256 + k + 1) * 256 + n0];
            float2 a2 = *(const float2*)&W[(256 + k + 2) * 256 + n0];
            float2 a3 = *(const float2*)&W[(256 + k + 3) * 256 + n0];
            float2 c0_ = *(const float2*)&W[(512 + k + 0) * 256 + n0];
            float2 c1_ = *(const float2*)&W[(512 + k + 1) * 256 + n0];
            float2 c2_ = *(const float2*)&W[(512 + k + 2) * 256 + n0];
            float2 c3_ = *(const float2*)&W[(512 + k + 3) * 256 + n0];
            sh0 += mu4.x * a0.x + mu4.y * a1.x + mu4.z * a2.x + mu4.w * a3.x
                 + md4.x * c0_.x + md4.y * c1_.x + md4.z * c2_.x + md4.w * c3_.x;
            sh1 += mu4.x * a0.y + mu4.y * a1.y + mu4.z * a2.y + mu4.w * a3.y
                 + md4.x * c0_.y + md4.y * c1_.y + md4.z * c2_.y + md4.w * c3_.y;
        }
        sh[w_][n0] = sh0; sh[w_][n0 + 1] = sh1;
    }
    __syncthreads();

    // ---- phase 1: thread = (walker, elec-half, 4 cols)
    const int w_   = tid >> 7;
    const int inr  = tid & 127;
    const int half = inr >> 6;
    const int e0   = half * 8;
    const int c0   = (inr & 63) * 4;

    float acc[8][4];
#pragma unroll
    for (int e = 0; e < 8; ++e)
#pragma unroll
        for (int jj = 0; jj < 4; ++jj) acc[e][jj] = 0.f;

    // s part: W rows [0,256), unroll x8 with batched loads
    for (int k = 0; k < 256; k += 8) {
        float4 wr[8];
#pragma unroll
        for (int q = 0; q < 8; ++q) wr[q] = *(const float4*)&W[(k + q) * 256 + c0];
#pragma unroll
        for (int e = 0; e < 8; ++e) {
            float4 sa = *(const float4*)&sOld[w_][e0 + e][k];
            float4 sb4 = *(const float4*)&sOld[w_][e0 + e][k + 4];
            acc[e][0] += sa.x * wr[0].x + sa.y * wr[1].x + sa.z * wr[2].x + sa.w * wr[3].x
                       + sb4.x * wr[4].x + sb4.y * wr[5].x + sb4.z * wr[6].x + sb4.w * wr[7].x;
            acc[e][1] += sa.x * wr[0].y + sa.y * wr[1].y + sa.z * wr[2].y + sa.w * wr[3].y
                       + sb4.x * wr[4].y + sb4.y * wr[5].y + sb4.z * wr[6].y + sb4.w * wr[7].y;
            acc[e][2] += sa.x * wr[0].z + sa.y * wr[1].z + sa.z * wr[2].z + sa.w * wr[3].z
                       + sb4.x * wr[4].z + sb4.y * wr[5].z + sb4.z * wr[6].z + sb4.w * wr[7].z;
            acc[e][3] += sa.x * wr[0].w + sa.y * wr[1].w + sa.z * wr[2].w + sa.w * wr[3].w
                       + sb4.x * wr[4].w + sb4.y * wr[5].w + sb4.z * wr[6].w + sb4.w * wr[7].w;
        }
    }
    // p part: W rows [768,832) <-> pupd[w][e][q]
    for (int k = 0; k < 64; k += 8) {
        float4 wr[8];
#pragma unroll
        for (int q = 0; q < 8; ++q) wr[q] = *(const float4*)&W[(768 + k + q) * 256 + c0];
#pragma unroll
        for (int e = 0; e < 8; ++e) {
            float4 pa = *(const float4*)&pupd[w_][e0 + e][k];
            float4 pb4 = *(const float4*)&pupd[w_][e0 + e][k + 4];
            acc[e][0] += pa.x * wr[0].x + pa.y * wr[1].x + pa.z * wr[2].x + pa.w * wr[3].x
                       + pb4.x * wr[4].x + pb4.y * wr[5].x + pb4.z * wr[6].x + pb4.w * wr[7].x;
            acc[e][1] += pa.x * wr[0].y + pa.y * wr[1].y + pa.z * wr[2].y + pa.w * wr[3].y
                       + pb4.x * wr[4].y + pb4.y * wr[5].y + pb4.z * wr[6].y + pb4.w * wr[7].y;
            acc[e][2] += pa.x * wr[0].z + pa.y * wr[1].z + pa.z * wr[2].z + pa.w * wr[3].z
                       + pb4.x * wr[4].z + pb4.y * wr[5].z + pb4.z * wr[6].z + pb4.w * wr[7].z;
            acc[e][3] += pa.x * wr[0].w + pa.y * wr[1].w + pa.z * wr[2].w + pa.w * wr[3].w
                       + pb4.x * wr[4].w + pb4.y * wr[5].w + pb4.z * wr[6].w + pb4.w * wr[7].w;
        }
    }

    float* sv_bw = s_v + (size_t)(b2 * 2 + w_) * 4096;
    float msum[4] = {0.f, 0.f, 0.f, 0.f};
#pragma unroll
    for (int e = 0; e < 8; ++e) {
        float v[4];
#pragma unroll
        for (int jj = 0; jj < 4; ++jj) {
            v[jj] = fast_tanh(acc[e][jj] + sh[w_][c0 + jj]);
            if (residual) v[jj] += sOld[w_][e0 + e][c0 + jj];
            msum[jj] += v[jj];
        }
        *(float4*)&sv_bw[(e0 + e) * 256 + c0] = make_float4(v[0], v[1], v[2], v[3]);
    }
    if (write_means) {
        float* smw = smean + (size_t)(b2 * 2 + w_) * 512 + half * 256;
        *(float4*)&smw[c0] = make_float4(msum[0] * 0.125f, msum[1] * 0.125f,
                                         msum[2] * 0.125f, msum[3] * 0.125f);
    }
}

// ---------------------------------------------------------------------------
// Orbitals: sw = s_final[:,spin] @ W + b, * env; write orb (B,2,16(det),8(j),8(i))
// ---------------------------------------------------------------------------
__global__ __launch_bounds__(256) void k_orb(
    const float* __restrict__ r, const float* __restrict__ a,
    const float* __restrict__ s_v,
    const float* __restrict__ wuW, const float* __restrict__ wub,
    const float* __restrict__ wdW, const float* __restrict__ wdb,
    float* __restrict__ orb)
{
    const int b   = blockIdx.x;
    const int tid = threadIdx.x;
    __shared__ float sF[16][256];
    __shared__ float envl[16];
    const float* sv_b = s_v + (size_t)b * 4096;
    float* sFF = &sF[0][0];
    for (int t = tid * 4; t < 4096; t += 1024)
        *(float4*)&sFF[t] = *(const float4*)&sv_b[t];
    if (tid < 16) {
        float ex = 0.f;
#pragma unroll
        for (int at = 0; at < 4; ++at) {
            float dx = r[b * 48 + tid * 3 + 0] - a[at * 3 + 0];
            float dy = r[b * 48 + tid * 3 + 1] - a[at * 3 + 1];
            float dz = r[b * 48 + tid * 3 + 2] - a[at * 3 + 2];
            ex += __expf(-sqrtf(dx * dx + dy * dy + dz * dz));
        }
        envl[tid] = ex;
    }
    __syncthreads();

    const int spin = tid >> 7;
    const int c    = tid & 127;
    const float* Wm = spin ? wdW : wuW;
    const float* bm = spin ? wdb : wub;
    const int e0 = spin * 8;
    float acc[8];
    const float bias = bm[c];
#pragma unroll
    for (int e = 0; e < 8; ++e) acc[e] = bias;
    for (int k = 0; k < 256; k += 4) {
        float w0 = Wm[(k + 0) * 128 + c];
        float w1 = Wm[(k + 1) * 128 + c];
        float w2 = Wm[(k + 2) * 128 + c];
        float w3 = Wm[(k + 3) * 128 + c];
#pragma unroll
        for (int e = 0; e < 8; ++e) {
            float4 s4 = *(const float4*)&sF[e0 + e][k];
            acc[e] += s4.x * w0 + s4.y * w1 + s4.z * w2 + s4.w * w3;
        }
    }
    const int d = c & 15, jrow = c >> 4;
    float out[8];
#pragma unroll
    for (int e = 0; e < 8; ++e) out[e] = acc[e] * envl[e0 + e];
    float* dst = orb + ((size_t)((b * 2 + spin) * 16 + d) * 8 + jrow) * 8;
    *(float4*)dst       = make_float4(out[0], out[1], out[2], out[3]);
    *(float4*)(dst + 4) = make_float4(out[4], out[5], out[6], out[7]);
}

// ---------------------------------------------------------------------------
// slogdet of 8x8 (partial pivoting, fully unrolled) + det-combine + logsumexp
// ---------------------------------------------------------------------------
__device__ __forceinline__ void slogdet8(float M[8][8], float& sgn_out, float& ld_out) {
    float sgn = 1.f, ld = 0.f;
#pragma unroll
    for (int k = 0; k < 8; ++k) {
        float best = fabsf(M[k][k]);
        int p = k;
#pragma unroll
        for (int rr = k + 1; rr < 8; ++rr) {
            float v = fabsf(M[rr][k]);
            if (v > best) { best = v; p = rr; }
        }
        if (p != k) sgn = -sgn;
#pragma unroll
        for (int rr = k + 1; rr < 8; ++rr) {
            bool sw = (rr == p);
#pragma unroll
            for (int cc = k; cc < 8; ++cc) {
                float x = M[k][cc], y = M[rr][cc];
                M[k][cc]  = sw ? y : x;
                M[rr][cc] = sw ? x : y;
            }
        }
        float piv = M[k][k];
        if (piv < 0.f) sgn = -sgn;
        ld += logf(fabsf(piv));
        float inv = 1.f / piv;
#pragma unroll
        for (int rr = k + 1; rr < 8; ++rr) {
            float f = M[rr][k] * inv;
#pragma unroll
            for (int cc = k + 1; cc < 8; ++cc) M[rr][cc] -= f * M[k][cc];
        }
    }
    sgn_out = sgn; ld_out = ld;
}

__global__ __launch_bounds__(256) void k_det(
    const float* __restrict__ orb, const float* __restrict__ wfW,
    float* __restrict__ out)
{
    const int g = blockIdx.x * 256 + threadIdx.x;
    const int b = g >> 4, d = g & 15;
    float M[8][8];
    const float* src = orb + (size_t)((b * 2 + 0) * 16 + d) * 64;
#pragma unroll
    for (int rr = 0; rr < 8; ++rr) {
        float4 v0 = *(const float4*)&src[rr * 8];
        float4 v1 = *(const float4*)&src[rr * 8 + 4];
        M[rr][0] = v0.x; M[rr][1] = v0.y; M[rr][2] = v0.z; M[rr][3] = v0.w;
        M[rr][4] = v1.x; M[rr][5] = v1.y; M[rr][6] = v1.z; M[rr][7] = v1.w;
    }
    float s1, l1; slogdet8(M, s1, l1);
    src = orb + (size_t)((b * 2 + 1) * 16 + d) * 64;
#pragma unroll
    for (int rr = 0; rr < 8; ++rr) {
        float4 v0 = *(const float4*)&src[rr * 8];
        float4 v1 = *(const float4*)&src[rr * 8 + 4];
        M[rr][0] = v0.x; M[rr][1] = v0.y; M[rr][2] = v0.z; M[rr][3] = v0.w;
        M[rr][4] = v1.x; M[rr][5] = v1.y; M[rr][6] = v1.z; M[rr][7] = v1.w;
    }
    float s2, l2; slogdet8(M, s2, l2);
    float sgn = s1 * s2;
    float ld  = l1 + l2;

    float m = ld;
    m = fmaxf(m, __shfl_xor(m, 1));
    m = fmaxf(m, __shfl_xor(m, 2));
    m = fmaxf(m, __shfl_xor(m, 4));
    m = fmaxf(m, __shfl_xor(m, 8));
    float sub = sgn * __expf(ld - m) * wfW[d];
    sub += __shfl_xor(sub, 1);
    sub += __shfl_xor(sub, 2);
    sub += __shfl_xor(sub, 4);
    sub += __shfl_xor(sub, 8);
    if (d == 0) out[b] = logf(fabsf(sub)) + m;
}

// ---------------------------------------------------------------------------
extern "C" void kernel_launch(void* const* d_in, const int* in_sizes, int n_in,
                              void* d_out, int out_size, void* d_ws, size_t ws_size,
                              hipStream_t stream) {
    (void)in_sizes; (void)n_in; (void)out_size; (void)ws_size;
    const float* r   = (const float*)d_in[0];
    const float* a   = (const float*)d_in[1];
    const float* sW0 = (const float*)d_in[2];
    const float* sb0 = (const float*)d_in[3];
    const float* sW  = (const float*)d_in[4];
    const float* sb  = (const float*)d_in[5];
    const float* pW0 = (const float*)d_in[6];
    const float* pb0 = (const float*)d_in[7];
    const float* pW  = (const float*)d_in[8];
    const float* pb  = (const float*)d_in[9];
    const float* vW  = (const float*)d_in[10];
    const float* vb  = (const float*)d_in[11];
    const float* wuW = (const float*)d_in[12];
    const float* wub = (const float*)d_in[13];
    const float* wdW = (const float*)d_in[14];
    const float* wdb = (const float*)d_in[15];
    const float* wfW = (const float*)d_in[16];
    float* out = (float*)d_out;

    float* ws     = (float*)d_ws;
    float* pmeans = ws;                          // 5 * 2,097,152 = 10,485,760 floats
    float* s_v    = ws + (size_t)5 * STAGE_SZ;   // 8,388,608 floats
    float* smean  = s_v + (size_t)NB * 4096;     // 1,048,576 floats
    float* orb    = pmeans;                      // alias: stages 0-1 dead by k_orb time

    k_pstream<<<NB, 1024, 0, stream>>>(r, pW0, pb0, pW, pb, pmeans);
    k_s0<<<NB, 256, 0, stream>>>(r, a, sW0, sb0, s_v, smean);
    for (int l = 0; l < 4; ++l) {
        k_slayer<<<NB / 2, 256, 0, stream>>>(sW + (size_t)l * 832 * 256, sb + l * 256,
                                             pmeans + (size_t)l * STAGE_SZ,
                                             s_v, smean, 1, 1);
    }
    k_slayer<<<NB / 2, 256, 0, stream>>>(vW, vb, pmeans + (size_t)4 * STAGE_SZ,
                                         s_v, smean, 0, 0);
    k_orb<<<NB, 256, 0, stream>>>(r, a, s_v, wuW, wub, wdW, wdb, orb);
    k_det<<<NB / 16, 256, 0, stream>>>(orb, wfW, out);
}

// Round 7
// 753.837 us; speedup vs baseline: 2.6212x; 1.3010x over previous
//
#include <hip/hip_runtime.h>
#include <math.h>

#define NB 2048
#define PM_STAGE 2097152   // elements per pmeans stage (2048*16*2*32)
#define BPK_L    81920     // elements per packed weight layer (10*16*64*8)

typedef float    f32x4 __attribute__((ext_vector_type(4)));
typedef _Float16 f16x8 __attribute__((ext_vector_type(8)));

__device__ __forceinline__ float fast_tanh(float x) {
    float ax = fabsf(x);
    float e  = __expf(2.0f * ax);
    float t  = 1.0f - 2.0f / (e + 1.0f);
    return copysignf(t, x);
}

__device__ __forceinline__ void split16(float x, _Float16& hi, _Float16& lo) {
    hi = (_Float16)x;
    lo = (_Float16)(x - (float)hi);
}

// ---------------------------------------------------------------------------
// One-time weight pack -> f16 hi/lo B-fragments for the PER-ELECTRON part only
// (A-features: [s 0..255 | pu 256..287 | pd 288..319] -> W rows f / 768+ / 800+).
// Bpk[l][kc(10)][nt(16)][lane(64)][j(8)]; layers 0..3 = sW[l], 4 = vW.
// B-frag: lane holds B[k = kc*32 + (lane>>4)*8 + j][n = nt*16 + (lane&15)].
// ---------------------------------------------------------------------------
__global__ __launch_bounds__(256) void k_prep_w(
    const float* __restrict__ sW, const float* __restrict__ vW,
    _Float16* __restrict__ Bhi, _Float16* __restrict__ Blo)
{
    const int blk = blockIdx.x;       // l*10 + kc
    const int l   = blk / 10;
    const int kc  = blk % 10;
    const float* Wsrc = (l < 4) ? (sW + (size_t)l * 212992) : vW;
    const int lane = threadIdx.x & 63;
    const int sub  = threadIdx.x >> 6;
    const size_t base = (size_t)l * BPK_L + (size_t)kc * 8192;
#pragma unroll
    for (int ntl = 0; ntl < 4; ++ntl) {
        const int nt = sub * 4 + ntl;
        const int n  = nt * 16 + (lane & 15);
#pragma unroll
        for (int j = 0; j < 8; ++j) {
            const int f = kc * 32 + (lane >> 4) * 8 + j;   // 0..319
            int row;
            if (f < 256)      row = f;
            else if (f < 288) row = 768 + (f - 256);
            else              row = 800 + (f - 288);
            const float w = Wsrc[row * 256 + n];
            _Float16 hi, lo; split16(w, hi, lo);
            Bhi[base + (size_t)(nt * 64 + lane) * 8 + j] = hi;
            Blo[base + (size_t)(nt * 64 + lane) * 8 + j] = lo;
        }
    }
}

// ---------------------------------------------------------------------------
// p-stream (R4 design); emits f16 hi/lo spin means.
// pmeans layout per stage: (B, 16(j), 2(h), 32)
// ---------------------------------------------------------------------------
__global__ __launch_bounds__(1024) void k_pstream(
    const float* __restrict__ r,
    const float* __restrict__ pW0, const float* __restrict__ pb0,
    const float* __restrict__ pW,  const float* __restrict__ pb,
    _Float16* __restrict__ pm_hi, _Float16* __restrict__ pm_lo)
{
    const int b    = blockIdx.x;
    const int tid  = threadIdx.x;
    const int lane = tid & 63;
    const int wv   = __builtin_amdgcn_readfirstlane(tid >> 6);
    const int pg   = wv & 3;
    const int k0   = (wv >> 2) * 8;
    const int pair = pg * 64 + lane;
    const int i    = pair >> 4;
    const int j    = pair & 15;

    __shared__ float rl[48];
    __shared__ float pst[32][257];

    if (tid < 48) rl[tid] = r[b * 48 + tid];
    __syncthreads();

    const float dx = rl[j * 3 + 0] - rl[i * 3 + 0];
    const float dy = rl[j * 3 + 1] - rl[i * 3 + 1];
    const float dz = rl[j * 3 + 2] - rl[i * 3 + 2];
    const float ee = (i == j) ? 1.0f : 0.0f;
    const float len = sqrtf((dx + ee) * (dx + ee) + (dy + ee) * (dy + ee) + (dz + ee) * (dz + ee));

    float pcur[8];
#pragma unroll
    for (int kk = 0; kk < 8; ++kk) {
        const int k = k0 + kk;
        float acc = pb0[k];
        acc += dx  * pW0[0 * 32 + k];
        acc += dy  * pW0[1 * 32 + k];
        acc += dz  * pW0[2 * 32 + k];
        acc += len * pW0[3 * 32 + k];
        pcur[kk] = fast_tanh(acc);
        pst[k0 + kk][pair] = pcur[kk];
    }
    __syncthreads();

    {
        const int o  = tid;
        const int mj = o >> 6, mh = (o >> 5) & 1, mk = o & 31;
        float s = 0.f;
#pragma unroll
        for (int i8 = 0; i8 < 8; ++i8) s += pst[mk][(mh * 8 + i8) * 16 + mj];
        _Float16 hi, lo; split16(s * 0.125f, hi, lo);
        pm_hi[(size_t)b * 1024 + o] = hi;
        pm_lo[(size_t)b * 1024 + o] = lo;
    }

    for (int l = 0; l < 4; ++l) {
        const float* __restrict__ Wl = pW + l * 1024;
        float acc[8];
#pragma unroll
        for (int kk = 0; kk < 8; ++kk) acc[kk] = pb[l * 32 + k0 + kk];
#pragma unroll
        for (int m = 0; m < 32; ++m) {
            const float f = pst[m][pair];
            const float* wrow = Wl + m * 32 + k0;
#pragma unroll
            for (int kk = 0; kk < 8; ++kk) acc[kk] += f * wrow[kk];
        }
        __syncthreads();
#pragma unroll
        for (int kk = 0; kk < 8; ++kk) {
            pcur[kk] = fast_tanh(acc[kk]) + pcur[kk];
            pst[k0 + kk][pair] = pcur[kk];
        }
        __syncthreads();
        {
            const int o  = tid;
            const int mj = o >> 6, mh = (o >> 5) & 1, mk = o & 31;
            float s = 0.f;
#pragma unroll
            for (int i8 = 0; i8 < 8; ++i8) s += pst[mk][(mh * 8 + i8) * 16 + mj];
            _Float16 hi, lo; split16(s * 0.125f, hi, lo);
            pm_hi[(size_t)(l + 1) * PM_STAGE + (size_t)b * 1024 + o] = hi;
            pm_lo[(size_t)(l + 1) * PM_STAGE + (size_t)b * 1024 + o] = lo;
        }
    }
}

// ---------------------------------------------------------------------------
// Layer 0: embedding + first s layer (fp32). Writes s hi/lo (f16).
// ---------------------------------------------------------------------------
__global__ __launch_bounds__(256) void k_s0(
    const float* __restrict__ r, const float* __restrict__ a,
    const float* __restrict__ sW0, const float* __restrict__ sb0,
    _Float16* __restrict__ s_hi, _Float16* __restrict__ s_lo)
{
    const int b   = blockIdx.x;
    const int tid = threadIdx.x;
    __shared__ float rl[48];
    __shared__ float al[12];
    __shared__ float pin[16][16][4];
    __shared__ float se[16][16];
    __shared__ float sm0[2][16];
    __shared__ float pm0[16][2][4];
    __shared__ float blk[16][56];

    if (tid < 48) rl[tid] = r[b * 48 + tid];
    if (tid >= 64 && tid < 76) al[tid - 64] = a[tid - 64];
    __syncthreads();
    {
        const int i = tid & 15, j = tid >> 4;
        float dx = rl[j * 3 + 0] - rl[i * 3 + 0];
        float dy = rl[j * 3 + 1] - rl[i * 3 + 1];
        float dz = rl[j * 3 + 2] - rl[i * 3 + 2];
        float ee = (i == j) ? 1.0f : 0.0f;
        float len = sqrtf((dx + ee) * (dx + ee) + (dy + ee) * (dy + ee) + (dz + ee) * (dz + ee));
        pin[j][i][0] = dx; pin[j][i][1] = dy; pin[j][i][2] = dz; pin[j][i][3] = len;
    }
    if (tid < 16) {
        const int e = tid;
#pragma unroll
        for (int at = 0; at < 4; ++at) {
            float dx = rl[e * 3 + 0] - al[at * 3 + 0];
            float dy = rl[e * 3 + 1] - al[at * 3 + 1];
            float dz = rl[e * 3 + 2] - al[at * 3 + 2];
            float ln = sqrtf(dx * dx + dy * dy + dz * dz);
            se[e][at * 4 + 0] = dx; se[e][at * 4 + 1] = dy;
            se[e][at * 4 + 2] = dz; se[e][at * 4 + 3] = ln;
        }
    }
    __syncthreads();
    if (tid < 32) {
        const int h = tid >> 4, f = tid & 15;
        float s = 0.f;
        for (int e = 0; e < 8; ++e) s += se[h * 8 + e][f];
        sm0[h][f] = s * 0.125f;
    }
    if (tid < 128) {
        const int j = tid >> 3, h = (tid >> 2) & 1, f = tid & 3;
        float s = 0.f;
        for (int i2 = 0; i2 < 8; ++i2) s += pin[j][h * 8 + i2][f];
        pm0[j][h][f] = s * 0.125f;
    }
    __syncthreads();
    for (int t = tid; t < 16 * 56; t += 256) {
        const int e = t / 56, k = t % 56;
        float v;
        if (k < 16)      v = se[e][k];
        else if (k < 32) v = sm0[0][k - 16];
        else if (k < 48) v = sm0[1][k - 32];
        else if (k < 52) v = pm0[e][0][k - 48];
        else             v = pm0[e][1][k - 52];
        blk[e][k] = v;
    }
    __syncthreads();

    const int n = tid;
    float acc[16];
#pragma unroll
    for (int e = 0; e < 16; ++e) acc[e] = sb0[n];
    for (int k = 0; k < 56; k += 4) {
        float w0 = sW0[(k + 0) * 256 + n];
        float w1 = sW0[(k + 1) * 256 + n];
        float w2 = sW0[(k + 2) * 256 + n];
        float w3 = sW0[(k + 3) * 256 + n];
#pragma unroll
        for (int e = 0; e < 16; ++e) {
            float4 s4 = *(const float4*)&blk[e][k];
            acc[e] += s4.x * w0 + s4.y * w1 + s4.z * w2 + s4.w * w3;
        }
    }
    _Float16* sh_b = s_hi + (size_t)b * 4096;
    _Float16* sl_b = s_lo + (size_t)b * 4096;
#pragma unroll
    for (int e = 0; e < 16; ++e) {
        float v = fast_tanh(acc[e]);
        _Float16 hi, lo; split16(v, hi, lo);
        sh_b[e * 256 + n] = hi;
        sl_b[e * 256 + n] = lo;
    }
}

// ---------------------------------------------------------------------------
// Shared (row-constant) part, exact fp32:
//   Zsh[b][n] = bias[n] + mu_b . W[256:512][:,n] + md_b . W[512:768][:,n]
// Block = 8 walkers, 512 threads. Phase 1: means (from s hi+lo) into LDS.
// Phase 2: 64 threads/walker x 4 cols, K=256 fp32 FMA.
// ---------------------------------------------------------------------------
__global__ __launch_bounds__(512) void k_shared(
    const _Float16* __restrict__ s_hi, const _Float16* __restrict__ s_lo,
    const float* __restrict__ W, const float* __restrict__ bias,
    float* __restrict__ Zsh)
{
    const int b0  = blockIdx.x * 8;
    const int tid = threadIdx.x;
    __shared__ float mean[8][2][256];   // 16 KB

    {
        const int v0 = tid * 8;
        const int w  = v0 >> 9, h = (v0 >> 8) & 1, k0 = v0 & 255;
        float acc[8] = {0.f, 0.f, 0.f, 0.f, 0.f, 0.f, 0.f, 0.f};
        for (int e = 0; e < 8; ++e) {
            const size_t base = ((size_t)(b0 + w) * 16 + h * 8 + e) * 256 + k0;
#pragma unroll
            for (int kk = 0; kk < 8; ++kk)
                acc[kk] += (float)s_hi[base + kk] + (float)s_lo[base + kk];
        }
#pragma unroll
        for (int kk = 0; kk < 8; ++kk) mean[w][h][k0 + kk] = acc[kk] * 0.125f;
    }
    __syncthreads();

    const int w2 = tid >> 6;
    const int n0 = (tid & 63) * 4;
    float4 z = make_float4(bias[n0], bias[n0 + 1], bias[n0 + 2], bias[n0 + 3]);
#pragma unroll 4
    for (int k = 0; k < 256; ++k) {
        const float mu = mean[w2][0][k];
        const float md = mean[w2][1][k];
        float4 wmu = *(const float4*)&W[(256 + k) * 256 + n0];
        float4 wmd = *(const float4*)&W[(512 + k) * 256 + n0];
        z.x += mu * wmu.x + md * wmd.x;
        z.y += mu * wmu.y + md * wmd.y;
        z.z += mu * wmu.z + md * wmd.z;
        z.w += mu * wmu.w + md * wmd.w;
    }
    *(float4*)&Zsh[(size_t)(b0 + w2) * 256 + n0] = z;
}

// ---------------------------------------------------------------------------
// Split-f16 MFMA s-layer (per-electron part, K=320). Block = 4 walkers (M=64),
// 4 waves; wave wv covers n-tiles wv*4..wv*4+3.
// acc += Ahi*Bhi + Ahi*Blo + Alo*Bhi + Alo*Blo  (== exact fp32-level product).
// kc 0..7 = s, kc 8..9 = pu/pd. Epilogue: + Zsh (bias+mean part), tanh,
// + residual (hi+lo), split-store. __syncthreads guards the in-place WAR.
// MFMA layouts (m89/m120): A[m=lane&15][k=quad*8+j]; B[n=lane&15][k=quad*8+j];
// D col=lane&15, row=quad*4+reg.
// ---------------------------------------------------------------------------
__global__ __launch_bounds__(256, 2) void k_gemm(
    _Float16* __restrict__ s_hi, _Float16* __restrict__ s_lo,
    const _Float16* __restrict__ pm_hi, const _Float16* __restrict__ pm_lo,
    const _Float16* __restrict__ Bhi, const _Float16* __restrict__ Blo,
    const float* __restrict__ Zsh,
    int is_final)
{
    const int tid  = threadIdx.x;
    const int lane = tid & 63;
    const int wv   = tid >> 6;
    const int m16  = lane & 15;
    const int quad = lane >> 4;
    const int wb   = blockIdx.x * 4;
    const int n0   = wv * 64;

    f32x4 acc[4][4];
#pragma unroll
    for (int mt = 0; mt < 4; ++mt)
#pragma unroll
        for (int nt = 0; nt < 4; ++nt) acc[mt][nt] = (f32x4){0.f, 0.f, 0.f, 0.f};

    int aS[4], aP[4];
#pragma unroll
    for (int mt = 0; mt < 4; ++mt) {
        aS[mt] = ((wb + mt) * 16 + m16) * 256 + quad * 8;
        aP[mt] = ((wb + mt) * 16 + m16) * 64  + quad * 8;
    }
    const _Float16* Bhw = Bhi + (size_t)(wv * 4) * 512 + (size_t)lane * 8;
    const _Float16* Blw = Blo + (size_t)(wv * 4) * 512 + (size_t)lane * 8;

    // ---- s part: kc 0..7
#pragma unroll
    for (int kc = 0; kc < 8; ++kc) {
        f16x8 ah[4], al[4];
#pragma unroll
        for (int mt = 0; mt < 4; ++mt) {
            ah[mt] = *(const f16x8*)(s_hi + aS[mt] + kc * 32);
            al[mt] = *(const f16x8*)(s_lo + aS[mt] + kc * 32);
        }
#pragma unroll
        for (int nt = 0; nt < 4; ++nt) {
            f16x8 bh = *(const f16x8*)(Bhw + (size_t)kc * 8192 + nt * 512);
            f16x8 bl = *(const f16x8*)(Blw + (size_t)kc * 8192 + nt * 512);
#pragma unroll
            for (int mt = 0; mt < 4; ++mt) {
                acc[mt][nt] = __builtin_amdgcn_mfma_f32_16x16x32_f16(ah[mt], bh, acc[mt][nt], 0, 0, 0);
                acc[mt][nt] = __builtin_amdgcn_mfma_f32_16x16x32_f16(ah[mt], bl, acc[mt][nt], 0, 0, 0);
                acc[mt][nt] = __builtin_amdgcn_mfma_f32_16x16x32_f16(al[mt], bh, acc[mt][nt], 0, 0, 0);
                acc[mt][nt] = __builtin_amdgcn_mfma_f32_16x16x32_f16(al[mt], bl, acc[mt][nt], 0, 0, 0);
            }
        }
    }
    // ---- p part: kc 8..9 (pu, pd)
#pragma unroll
    for (int h = 0; h < 2; ++h) {
        f16x8 ah[4], al[4];
#pragma unroll
        for (int mt = 0; mt < 4; ++mt) {
            ah[mt] = *(const f16x8*)(pm_hi + aP[mt] + h * 32);
            al[mt] = *(const f16x8*)(pm_lo + aP[mt] + h * 32);
        }
#pragma unroll
        for (int nt = 0; nt < 4; ++nt) {
            f16x8 bh = *(const f16x8*)(Bhw + (size_t)(8 + h) * 8192 + nt * 512);
            f16x8 bl = *(const f16x8*)(Blw + (size_t)(8 + h) * 8192 + nt * 512);
#pragma unroll
            for (int mt = 0; mt < 4; ++mt) {
                acc[mt][nt] = __builtin_amdgcn_mfma_f32_16x16x32_f16(ah[mt], bh, acc[mt][nt], 0, 0, 0);
                acc[mt][nt] = __builtin_amdgcn_mfma_f32_16x16x32_f16(ah[mt], bl, acc[mt][nt], 0, 0, 0);
                acc[mt][nt] = __builtin_amdgcn_mfma_f32_16x16x32_f16(al[mt], bh, acc[mt][nt], 0, 0, 0);
                acc[mt][nt] = __builtin_amdgcn_mfma_f32_16x16x32_f16(al[mt], bl, acc[mt][nt], 0, 0, 0);
            }
        }
    }

    __syncthreads();   // all A reads complete before in-place rewrite

    // ---- epilogue
#pragma unroll
    for (int mt = 0; mt < 4; ++mt) {
#pragma unroll
        for (int nt = 0; nt < 4; ++nt) {
            const int n  = n0 + nt * 16 + m16;
            const float zv = Zsh[(size_t)(wb + mt) * 256 + n];
            const int rowbase = (wb + mt) * 16 + quad * 4;
#pragma unroll
            for (int reg = 0; reg < 4; ++reg) {
                const int idx = (rowbase + reg) * 256 + n;
                float t = fast_tanh(acc[mt][nt][reg] + zv);
                if (!is_final) t += (float)s_hi[idx] + (float)s_lo[idx];
                _Float16 hi, lo; split16(t, hi, lo);
                s_hi[idx] = hi;
                s_lo[idx] = lo;
            }
        }
    }
}

// ---------------------------------------------------------------------------
// Orbitals: reconstruct s from hi/lo; write orb (B,2,16(det),8(j),8(i))
// ---------------------------------------------------------------------------
__global__ __launch_bounds__(256) void k_orb(
    const float* __restrict__ r, const float* __restrict__ a,
    const _Float16* __restrict__ s_hi, const _Float16* __restrict__ s_lo,
    const float* __restrict__ wuW, const float* __restrict__ wub,
    const float* __restrict__ wdW, const float* __restrict__ wdb,
    float* __restrict__ orb)
{
    const int b   = blockIdx.x;
    const int tid = threadIdx.x;
    __shared__ float sF[16][256];
    __shared__ float envl[16];
    {
        const _Float16* sh = s_hi + (size_t)b * 4096;
        const _Float16* sl = s_lo + (size_t)b * 4096;
        float* sFF = &sF[0][0];
        for (int t = tid; t < 4096; t += 256)
            sFF[t] = (float)sh[t] + (float)sl[t];
    }
    if (tid < 16) {
        float ex = 0.f;
#pragma unroll
        for (int at = 0; at < 4; ++at) {
            float dx = r[b * 48 + tid * 3 + 0] - a[at * 3 + 0];
            float dy = r[b * 48 + tid * 3 + 1] - a[at * 3 + 1];
            float dz = r[b * 48 + tid * 3 + 2] - a[at * 3 + 2];
            ex += __expf(-sqrtf(dx * dx + dy * dy + dz * dz));
        }
        envl[tid] = ex;
    }
    __syncthreads();

    const int spin = tid >> 7;
    const int c    = tid & 127;
    const float* Wm = spin ? wdW : wuW;
    const float* bm = spin ? wdb : wub;
    const int e0 = spin * 8;
    float acc[8];
    const float bias = bm[c];
#pragma unroll
    for (int e = 0; e < 8; ++e) acc[e] = bias;
    for (int k = 0; k < 256; k += 4) {
        float w0 = Wm[(k + 0) * 128 + c];
        float w1 = Wm[(k + 1) * 128 + c];
        float w2 = Wm[(k + 2) * 128 + c];
        float w3 = Wm[(k + 3) * 128 + c];
#pragma unroll
        for (int e = 0; e < 8; ++e) {
            float4 s4 = *(const float4*)&sF[e0 + e][k];
            acc[e] += s4.x * w0 + s4.y * w1 + s4.z * w2 + s4.w * w3;
        }
    }
    const int d = c & 15, jrow = c >> 4;
    float out[8];
#pragma unroll
    for (int e = 0; e < 8; ++e) out[e] = acc[e] * envl[e0 + e];
    float* dst = orb + ((size_t)((b * 2 + spin) * 16 + d) * 8 + jrow) * 8;
    *(float4*)dst       = make_float4(out[0], out[1], out[2], out[3]);
    *(float4*)(dst + 4) = make_float4(out[4], out[5], out[6], out[7]);
}

// ---------------------------------------------------------------------------
// slogdet of 8x8 + det-combine + logsumexp
// ---------------------------------------------------------------------------
__device__ __forceinline__ void slogdet8(float M[8][8], float& sgn_out, float& ld_out) {
    float sgn = 1.f, ld = 0.f;
#pragma unroll
    for (int k = 0; k < 8; ++k) {
        float best = fabsf(M[k][k]);
        int p = k;
#pragma unroll
        for (int rr = k + 1; rr < 8; ++rr) {
            float v = fabsf(M[rr][k]);
            if (v > best) { best = v; p = rr; }
        }
        if (p != k) sgn = -sgn;
#pragma unroll
        for (int rr = k + 1; rr < 8; ++rr) {
            bool sw = (rr == p);
#pragma unroll
            for (int cc = k; cc < 8; ++cc) {
                float x = M[k][cc], y = M[rr][cc];
                M[k][cc]  = sw ? y : x;
                M[rr][cc] = sw ? x : y;
            }
        }
        float piv = M[k][k];
        if (piv < 0.f) sgn = -sgn;
        ld += logf(fabsf(piv));
        float inv = 1.f / piv;
#pragma unroll
        for (int rr = k + 1; rr < 8; ++rr) {
            float f = M[rr][k] * inv;
#pragma unroll
            for (int cc = k + 1; cc < 8; ++cc) M[rr][cc] -= f * M[k][cc];
        }
    }
    sgn_out = sgn; ld_out = ld;
}

__global__ __launch_bounds__(256) void k_det(
    const float* __restrict__ orb, const float* __restrict__ wfW,
    float* __restrict__ out)
{
    const int g = blockIdx.x * 256 + threadIdx.x;
    const int b = g >> 4, d = g & 15;
    float M[8][8];
    const float* src = orb + (size_t)((b * 2 + 0) * 16 + d) * 64;
#pragma unroll
    for (int rr = 0; rr < 8; ++rr) {
        float4 v0 = *(const float4*)&src[rr * 8];
        float4 v1 = *(const float4*)&src[rr * 8 + 4];
        M[rr][0] = v0.x; M[rr][1] = v0.y; M[rr][2] = v0.z; M[rr][3] = v0.w;
        M[rr][4] = v1.x; M[rr][5] = v1.y; M[rr][6] = v1.z; M[rr][7] = v1.w;
    }
    float s1, l1; slogdet8(M, s1, l1);
    src = orb + (size_t)((b * 2 + 1) * 16 + d) * 64;
#pragma unroll
    for (int rr = 0; rr < 8; ++rr) {
        float4 v0 = *(const float4*)&src[rr * 8];
        float4 v1 = *(const float4*)&src[rr * 8 + 4];
        M[rr][0] = v0.x; M[rr][1] = v0.y; M[rr][2] = v0.z; M[rr][3] = v0.w;
        M[rr][4] = v1.x; M[rr][5] = v1.y; M[rr][6] = v1.z; M[rr][7] = v1.w;
    }
    float s2, l2; slogdet8(M, s2, l2);
    float sgn = s1 * s2;
    float ld  = l1 + l2;

    float m = ld;
    m = fmaxf(m, __shfl_xor(m, 1));
    m = fmaxf(m, __shfl_xor(m, 2));
    m = fmaxf(m, __shfl_xor(m, 4));
    m = fmaxf(m, __shfl_xor(m, 8));
    float sub = sgn * __expf(ld - m) * wfW[d];
    sub += __shfl_xor(sub, 1);
    sub += __shfl_xor(sub, 2);
    sub += __shfl_xor(sub, 4);
    sub += __shfl_xor(sub, 8);
    if (d == 0) out[b] = logf(fabsf(sub)) + m;
}

// ---------------------------------------------------------------------------
extern "C" void kernel_launch(void* const* d_in, const int* in_sizes, int n_in,
                              void* d_out, int out_size, void* d_ws, size_t ws_size,
                              hipStream_t stream) {
    (void)in_sizes; (void)n_in; (void)out_size; (void)ws_size;
    const float* r   = (const float*)d_in[0];
    const float* a   = (const float*)d_in[1];
    const float* sW0 = (const float*)d_in[2];
    const float* sb0 = (const float*)d_in[3];
    const float* sW  = (const float*)d_in[4];
    const float* sb  = (const float*)d_in[5];
    const float* pW0 = (const float*)d_in[6];
    const float* pb0 = (const float*)d_in[7];
    const float* pW  = (const float*)d_in[8];
    const float* pb  = (const float*)d_in[9];
    const float* vW  = (const float*)d_in[10];
    const float* vb  = (const float*)d_in[11];
    const float* wuW = (const float*)d_in[12];
    const float* wub = (const float*)d_in[13];
    const float* wdW = (const float*)d_in[14];
    const float* wdb = (const float*)d_in[15];
    const float* wfW = (const float*)d_in[16];
    float* out = (float*)d_out;

    // workspace layout (bytes), total 79,233,024 (< 79,691,776 known-safe)
    char* wsb = (char*)d_ws;
    _Float16* s_hi  = (_Float16*)(wsb + 0);          // 16,777,216
    _Float16* s_lo  = (_Float16*)(wsb + 16777216);   // 16,777,216
    _Float16* pm_hi = (_Float16*)(wsb + 33554432);   // 20,971,520 (5 stages)
    _Float16* pm_lo = (_Float16*)(wsb + 54525952);   // 20,971,520
    float*    Zsh   = (float*)   (wsb + 75497472);   //  2,097,152
    _Float16* Bhi   = (_Float16*)(wsb + 77594624);   //    819,200
    _Float16* Blo   = (_Float16*)(wsb + 78413824);   //    819,200
    float*    orb   = (float*)   (wsb + 33554432);   // 16,777,216 alias pm_hi (dead by k_orb)

    k_prep_w<<<50, 256, 0, stream>>>(sW, vW, Bhi, Blo);
    k_pstream<<<NB, 1024, 0, stream>>>(r, pW0, pb0, pW, pb, pm_hi, pm_lo);
    k_s0<<<NB, 256, 0, stream>>>(r, a, sW0, sb0, s_hi, s_lo);
    for (int l = 0; l < 4; ++l) {
        k_shared<<<NB / 8, 512, 0, stream>>>(s_hi, s_lo, sW + (size_t)l * 212992,
                                             sb + l * 256, Zsh);
        k_gemm<<<NB / 4, 256, 0, stream>>>(s_hi, s_lo,
                                           pm_hi + (size_t)l * PM_STAGE,
                                           pm_lo + (size_t)l * PM_STAGE,
                                           Bhi + (size_t)l * BPK_L,
                                           Blo + (size_t)l * BPK_L,
                                           Zsh, 0);
    }
    k_shared<<<NB / 8, 512, 0, stream>>>(s_hi, s_lo, vW, vb, Zsh);
    k_gemm<<<NB / 4, 256, 0, stream>>>(s_hi, s_lo,
                                       pm_hi + (size_t)4 * PM_STAGE,
                                       pm_lo + (size_t)4 * PM_STAGE,
                                       Bhi + (size_t)4 * BPK_L,
                                       Blo + (size_t)4 * BPK_L,
                                       Zsh, 1);
    k_orb<<<NB, 256, 0, stream>>>(r, a, s_hi, s_lo, wuW, wub, wdW, wdb, orb);
    k_det<<<NB / 16, 256, 0, stream>>>(orb, wfW, out);
}

// Round 8
// 671.028 us; speedup vs baseline: 2.9447x; 1.1234x over previous
//
#include <hip/hip_runtime.h>
#include <math.h>

#define NB 2048
#define PM_STAGE 2097152   // elements per pmeans stage (2048*16*2*32)
#define BPK_L    81920     // elements per packed weight layer (10*16*64*8)

typedef float    f32x4 __attribute__((ext_vector_type(4)));
typedef _Float16 f16x8 __attribute__((ext_vector_type(8)));

__device__ __forceinline__ float fast_tanh(float x) {
    float ax = fabsf(x);
    float e  = __expf(2.0f * ax);
    float t  = 1.0f - 2.0f / (e + 1.0f);
    return copysignf(t, x);
}

__device__ __forceinline__ void split16(float x, _Float16& hi, _Float16& lo) {
    hi = (_Float16)x;
    lo = (_Float16)(x - (float)hi);
}

// ---------------------------------------------------------------------------
// One-time weight pack -> f16 hi/lo B-fragments for the PER-ELECTRON part only
// (A-features: [s 0..255 | pu 256..287 | pd 288..319] -> W rows f / 768+ / 800+).
// Bpk[l][kc(10)][nt(16)][lane(64)][j(8)]; layers 0..3 = sW[l], 4 = vW.
// B-frag: lane holds B[k = kc*32 + (lane>>4)*8 + j][n = nt*16 + (lane&15)].
// ---------------------------------------------------------------------------
__global__ __launch_bounds__(256) void k_prep_w(
    const float* __restrict__ sW, const float* __restrict__ vW,
    _Float16* __restrict__ Bhi, _Float16* __restrict__ Blo)
{
    const int blk = blockIdx.x;       // l*10 + kc
    const int l   = blk / 10;
    const int kc  = blk % 10;
    const float* Wsrc = (l < 4) ? (sW + (size_t)l * 212992) : vW;
    const int lane = threadIdx.x & 63;
    const int sub  = threadIdx.x >> 6;
    const size_t base = (size_t)l * BPK_L + (size_t)kc * 8192;
#pragma unroll
    for (int ntl = 0; ntl < 4; ++ntl) {
        const int nt = sub * 4 + ntl;
        const int n  = nt * 16 + (lane & 15);
#pragma unroll
        for (int j = 0; j < 8; ++j) {
            const int f = kc * 32 + (lane >> 4) * 8 + j;   // 0..319
            int row;
            if (f < 256)      row = f;
            else if (f < 288) row = 768 + (f - 256);
            else              row = 800 + (f - 288);
            const float w = Wsrc[row * 256 + n];
            _Float16 hi, lo; split16(w, hi, lo);
            Bhi[base + (size_t)(nt * 64 + lane) * 8 + j] = hi;
            Blo[base + (size_t)(nt * 64 + lane) * 8 + j] = lo;
        }
    }
}

// ---------------------------------------------------------------------------
// One-time p-layer weight pack: pW (4,32,32) -> f16 hi/lo B-frags
// pBpk[l][nt(2)][lane(64)][j(8)]: lane holds B[k=(lane>>4)*8+j][n=nt*16+(lane&15)]
// ---------------------------------------------------------------------------
__global__ __launch_bounds__(128) void k_prep_p(
    const float* __restrict__ pW,
    _Float16* __restrict__ pBhi, _Float16* __restrict__ pBlo)
{
    const int l    = blockIdx.x;
    const int nt   = threadIdx.x >> 6;
    const int lane = threadIdx.x & 63;
    const int m16  = lane & 15, quad = lane >> 4;
#pragma unroll
    for (int j = 0; j < 8; ++j) {
        float w = pW[l * 1024 + (quad * 8 + j) * 32 + nt * 16 + m16];
        _Float16 hi, lo; split16(w, hi, lo);
        pBhi[((size_t)l * 2 + nt) * 512 + lane * 8 + j] = hi;
        pBlo[((size_t)l * 2 + nt) * 512 + lane * 8 + j] = lo;
    }
}

// ---------------------------------------------------------------------------
// p-stream via split-f16 MFMA. Block = 1 walker = 1024 threads = 16 waves;
// wave wv = m-tile (16 pairs). Pair state pst[feat][pair] in LDS (R7-verified
// layout/padding). Residual pcur stays fp32 in regs, held in D-layout
// (pair = wv*16+quad*4+reg, feats m16 / m16+16) which matches MFMA output —
// no layout round-trip. A-frags: 8 conflict-free b32 LDS gathers + split.
// 4 split terms -> ~exact fp32. pmeans layout per stage: (B,16(j),2(h),32).
// ---------------------------------------------------------------------------
__global__ __launch_bounds__(1024) void k_pstream(
    const float* __restrict__ r,
    const float* __restrict__ pW0, const float* __restrict__ pb0,
    const float* __restrict__ pb,
    const _Float16* __restrict__ pBhi, const _Float16* __restrict__ pBlo,
    _Float16* __restrict__ pm_hi, _Float16* __restrict__ pm_lo)
{
    const int b    = blockIdx.x;
    const int tid  = threadIdx.x;
    const int lane = tid & 63;
    const int wv   = __builtin_amdgcn_readfirstlane(tid >> 6);  // m-tile 0..15
    const int m16  = lane & 15;
    const int quad = lane >> 4;

    __shared__ float rl[48];
    __shared__ float pst[32][257];

    if (tid < 48) rl[tid] = r[b * 48 + tid];
    __syncthreads();

    const int f0 = m16, f1 = m16 + 16;
    float pcur[2][4];   // [nt][reg], D-layout residual state

    // ---- layer 0: per-thread geometry + tiny K=4 matvec for its D-positions
#pragma unroll
    for (int reg = 0; reg < 4; ++reg) {
        const int pair = wv * 16 + quad * 4 + reg;
        const int i = pair >> 4, j = pair & 15;
        float dx = rl[j * 3 + 0] - rl[i * 3 + 0];
        float dy = rl[j * 3 + 1] - rl[i * 3 + 1];
        float dz = rl[j * 3 + 2] - rl[i * 3 + 2];
        float ee = (i == j) ? 1.0f : 0.0f;
        float len = sqrtf((dx + ee) * (dx + ee) + (dy + ee) * (dy + ee) + (dz + ee) * (dz + ee));
#pragma unroll
        for (int nt = 0; nt < 2; ++nt) {
            const int k = nt ? f1 : f0;
            float acc = pb0[k] + dx * pW0[k] + dy * pW0[32 + k]
                      + dz * pW0[64 + k] + len * pW0[96 + k];
            float v = fast_tanh(acc);
            pcur[nt][reg] = v;
            pst[k][pair] = v;
        }
    }
    __syncthreads();

    // ---- stage-0 means (o = tid: j*64 + h*32 + k)
    {
        const int o = tid, mj = o >> 6, mh = (o >> 5) & 1, mk = o & 31;
        float s = 0.f;
#pragma unroll
        for (int i8 = 0; i8 < 8; ++i8) s += pst[mk][(mh * 8 + i8) * 16 + mj];
        _Float16 hi, lo; split16(s * 0.125f, hi, lo);
        pm_hi[(size_t)b * 1024 + o] = hi;
        pm_lo[(size_t)b * 1024 + o] = lo;
    }

    const int apair = wv * 16 + m16;   // this lane's A-row pair
    for (int l = 0; l < 4; ++l) {
        // A-frag gather + split (reads pst)
        f16x8 ah, al;
#pragma unroll
        for (int jj = 0; jj < 8; ++jj) {
            float v = pst[quad * 8 + jj][apair];
            _Float16 hi, lo; split16(v, hi, lo);
            ah[jj] = hi; al[jj] = lo;
        }
        // B-frags (global, L2-hot)
        const _Float16* bhp = pBhi + ((size_t)l * 2) * 512 + (size_t)lane * 8;
        const _Float16* blp = pBlo + ((size_t)l * 2) * 512 + (size_t)lane * 8;
        f32x4 acc0 = (f32x4){0.f, 0.f, 0.f, 0.f};
        f32x4 acc1 = (f32x4){0.f, 0.f, 0.f, 0.f};
        {
            f16x8 bh = *(const f16x8*)(bhp);
            f16x8 bl = *(const f16x8*)(blp);
            acc0 = __builtin_amdgcn_mfma_f32_16x16x32_f16(ah, bh, acc0, 0, 0, 0);
            acc0 = __builtin_amdgcn_mfma_f32_16x16x32_f16(ah, bl, acc0, 0, 0, 0);
            acc0 = __builtin_amdgcn_mfma_f32_16x16x32_f16(al, bh, acc0, 0, 0, 0);
            acc0 = __builtin_amdgcn_mfma_f32_16x16x32_f16(al, bl, acc0, 0, 0, 0);
            bh = *(const f16x8*)(bhp + 512);
            bl = *(const f16x8*)(blp + 512);
            acc1 = __builtin_amdgcn_mfma_f32_16x16x32_f16(ah, bh, acc1, 0, 0, 0);
            acc1 = __builtin_amdgcn_mfma_f32_16x16x32_f16(ah, bl, acc1, 0, 0, 0);
            acc1 = __builtin_amdgcn_mfma_f32_16x16x32_f16(al, bh, acc1, 0, 0, 0);
            acc1 = __builtin_amdgcn_mfma_f32_16x16x32_f16(al, bl, acc1, 0, 0, 0);
        }
        const float b0v = pb[l * 32 + f0];
        const float b1v = pb[l * 32 + f1];
        __syncthreads();   // all reads of old pst (A-gather + means) complete
#pragma unroll
        for (int reg = 0; reg < 4; ++reg) {
            const int pair = wv * 16 + quad * 4 + reg;
            pcur[0][reg] += fast_tanh(acc0[reg] + b0v);
            pcur[1][reg] += fast_tanh(acc1[reg] + b1v);
            pst[f0][pair] = pcur[0][reg];
            pst[f1][pair] = pcur[1][reg];
        }
        __syncthreads();   // new pst visible
        // stage l+1 means
        {
            const int o = tid, mj = o >> 6, mh = (o >> 5) & 1, mk = o & 31;
            float s = 0.f;
#pragma unroll
            for (int i8 = 0; i8 < 8; ++i8) s += pst[mk][(mh * 8 + i8) * 16 + mj];
            _Float16 hi, lo; split16(s * 0.125f, hi, lo);
            pm_hi[(size_t)(l + 1) * PM_STAGE + (size_t)b * 1024 + o] = hi;
            pm_lo[(size_t)(l + 1) * PM_STAGE + (size_t)b * 1024 + o] = lo;
        }
    }
}

// ---------------------------------------------------------------------------
// Layer 0: embedding + first s layer (fp32). Writes s hi/lo (f16).
// ---------------------------------------------------------------------------
__global__ __launch_bounds__(256) void k_s0(
    const float* __restrict__ r, const float* __restrict__ a,
    const float* __restrict__ sW0, const float* __restrict__ sb0,
    _Float16* __restrict__ s_hi, _Float16* __restrict__ s_lo)
{
    const int b   = blockIdx.x;
    const int tid = threadIdx.x;
    __shared__ float rl[48];
    __shared__ float al[12];
    __shared__ float pin[16][16][4];
    __shared__ float se[16][16];
    __shared__ float sm0[2][16];
    __shared__ float pm0[16][2][4];
    __shared__ float blk[16][56];

    if (tid < 48) rl[tid] = r[b * 48 + tid];
    if (tid >= 64 && tid < 76) al[tid - 64] = a[tid - 64];
    __syncthreads();
    {
        const int i = tid & 15, j = tid >> 4;
        float dx = rl[j * 3 + 0] - rl[i * 3 + 0];
        float dy = rl[j * 3 + 1] - rl[i * 3 + 1];
        float dz = rl[j * 3 + 2] - rl[i * 3 + 2];
        float ee = (i == j) ? 1.0f : 0.0f;
        float len = sqrtf((dx + ee) * (dx + ee) + (dy + ee) * (dy + ee) + (dz + ee) * (dz + ee));
        pin[j][i][0] = dx; pin[j][i][1] = dy; pin[j][i][2] = dz; pin[j][i][3] = len;
    }
    if (tid < 16) {
        const int e = tid;
#pragma unroll
        for (int at = 0; at < 4; ++at) {
            float dx = rl[e * 3 + 0] - al[at * 3 + 0];
            float dy = rl[e * 3 + 1] - al[at * 3 + 1];
            float dz = rl[e * 3 + 2] - al[at * 3 + 2];
            float ln = sqrtf(dx * dx + dy * dy + dz * dz);
            se[e][at * 4 + 0] = dx; se[e][at * 4 + 1] = dy;
            se[e][at * 4 + 2] = dz; se[e][at * 4 + 3] = ln;
        }
    }
    __syncthreads();
    if (tid < 32) {
        const int h = tid >> 4, f = tid & 15;
        float s = 0.f;
        for (int e = 0; e < 8; ++e) s += se[h * 8 + e][f];
        sm0[h][f] = s * 0.125f;
    }
    if (tid < 128) {
        const int j = tid >> 3, h = (tid >> 2) & 1, f = tid & 3;
        float s = 0.f;
        for (int i2 = 0; i2 < 8; ++i2) s += pin[j][h * 8 + i2][f];
        pm0[j][h][f] = s * 0.125f;
    }
    __syncthreads();
    for (int t = tid; t < 16 * 56; t += 256) {
        const int e = t / 56, k = t % 56;
        float v;
        if (k < 16)      v = se[e][k];
        else if (k < 32) v = sm0[0][k - 16];
        else if (k < 48) v = sm0[1][k - 32];
        else if (k < 52) v = pm0[e][0][k - 48];
        else             v = pm0[e][1][k - 52];
        blk[e][k] = v;
    }
    __syncthreads();

    const int n = tid;
    float acc[16];
#pragma unroll
    for (int e = 0; e < 16; ++e) acc[e] = sb0[n];
    for (int k = 0; k < 56; k += 4) {
        float w0 = sW0[(k + 0) * 256 + n];
        float w1 = sW0[(k + 1) * 256 + n];
        float w2 = sW0[(k + 2) * 256 + n];
        float w3 = sW0[(k + 3) * 256 + n];
#pragma unroll
        for (int e = 0; e < 16; ++e) {
            float4 s4 = *(const float4*)&blk[e][k];
            acc[e] += s4.x * w0 + s4.y * w1 + s4.z * w2 + s4.w * w3;
        }
    }
    _Float16* sh_b = s_hi + (size_t)b * 4096;
    _Float16* sl_b = s_lo + (size_t)b * 4096;
#pragma unroll
    for (int e = 0; e < 16; ++e) {
        float v = fast_tanh(acc[e]);
        _Float16 hi, lo; split16(v, hi, lo);
        sh_b[e * 256 + n] = hi;
        sl_b[e * 256 + n] = lo;
    }
}

// ---------------------------------------------------------------------------
// Shared (row-constant) part, exact fp32:
//   Zsh[b][n] = bias[n] + mu_b . W[256:512][:,n] + md_b . W[512:768][:,n]
// Block = 8 walkers, 512 threads.
// ---------------------------------------------------------------------------
__global__ __launch_bounds__(512) void k_shared(
    const _Float16* __restrict__ s_hi, const _Float16* __restrict__ s_lo,
    const float* __restrict__ W, const float* __restrict__ bias,
    float* __restrict__ Zsh)
{
    const int b0  = blockIdx.x * 8;
    const int tid = threadIdx.x;
    __shared__ float mean[8][2][256];   // 16 KB

    {
        const int v0 = tid * 8;
        const int w  = v0 >> 9, h = (v0 >> 8) & 1, k0 = v0 & 255;
        float acc[8] = {0.f, 0.f, 0.f, 0.f, 0.f, 0.f, 0.f, 0.f};
        for (int e = 0; e < 8; ++e) {
            const size_t base = ((size_t)(b0 + w) * 16 + h * 8 + e) * 256 + k0;
#pragma unroll
            for (int kk = 0; kk < 8; ++kk)
                acc[kk] += (float)s_hi[base + kk] + (float)s_lo[base + kk];
        }
#pragma unroll
        for (int kk = 0; kk < 8; ++kk) mean[w][h][k0 + kk] = acc[kk] * 0.125f;
    }
    __syncthreads();

    const int w2 = tid >> 6;
    const int n0 = (tid & 63) * 4;
    float4 z = make_float4(bias[n0], bias[n0 + 1], bias[n0 + 2], bias[n0 + 3]);
#pragma unroll 4
    for (int k = 0; k < 256; ++k) {
        const float mu = mean[w2][0][k];
        const float md = mean[w2][1][k];
        float4 wmu = *(const float4*)&W[(256 + k) * 256 + n0];
        float4 wmd = *(const float4*)&W[(512 + k) * 256 + n0];
        z.x += mu * wmu.x + md * wmd.x;
        z.y += mu * wmu.y + md * wmd.y;
        z.z += mu * wmu.z + md * wmd.z;
        z.w += mu * wmu.w + md * wmd.w;
    }
    *(float4*)&Zsh[(size_t)(b0 + w2) * 256 + n0] = z;
}

// ---------------------------------------------------------------------------
// Split-f16 MFMA s-layer (per-electron part, K=320). Block = 2 walkers (M=32),
// 4 waves; wave wv covers n-tiles wv*4..wv*4+3. Grid NB/2 (4+ blocks/CU for
// latency hiding — R7 had 2 blocks/CU at grid 512).
// acc += Ahi*Bhi + Ahi*Blo + Alo*Bhi + Alo*Blo.
// ---------------------------------------------------------------------------
__global__ __launch_bounds__(256, 4) void k_gemm(
    _Float16* __restrict__ s_hi, _Float16* __restrict__ s_lo,
    const _Float16* __restrict__ pm_hi, const _Float16* __restrict__ pm_lo,
    const _Float16* __restrict__ Bhi, const _Float16* __restrict__ Blo,
    const float* __restrict__ Zsh,
    int is_final)
{
    const int tid  = threadIdx.x;
    const int lane = tid & 63;
    const int wv   = tid >> 6;
    const int m16  = lane & 15;
    const int quad = lane >> 4;
    const int wb   = blockIdx.x * 2;
    const int n0   = wv * 64;

    f32x4 acc[2][4];
#pragma unroll
    for (int mt = 0; mt < 2; ++mt)
#pragma unroll
        for (int nt = 0; nt < 4; ++nt) acc[mt][nt] = (f32x4){0.f, 0.f, 0.f, 0.f};

    int aS[2], aP[2];
#pragma unroll
    for (int mt = 0; mt < 2; ++mt) {
        aS[mt] = ((wb + mt) * 16 + m16) * 256 + quad * 8;
        aP[mt] = ((wb + mt) * 16 + m16) * 64  + quad * 8;
    }
    const _Float16* Bhw = Bhi + (size_t)(wv * 4) * 512 + (size_t)lane * 8;
    const _Float16* Blw = Blo + (size_t)(wv * 4) * 512 + (size_t)lane * 8;

    // ---- s part: kc 0..7
#pragma unroll
    for (int kc = 0; kc < 8; ++kc) {
        f16x8 ah[2], al[2];
#pragma unroll
        for (int mt = 0; mt < 2; ++mt) {
            ah[mt] = *(const f16x8*)(s_hi + aS[mt] + kc * 32);
            al[mt] = *(const f16x8*)(s_lo + aS[mt] + kc * 32);
        }
#pragma unroll
        for (int nt = 0; nt < 4; ++nt) {
            f16x8 bh = *(const f16x8*)(Bhw + (size_t)kc * 8192 + nt * 512);
            f16x8 bl = *(const f16x8*)(Blw + (size_t)kc * 8192 + nt * 512);
#pragma unroll
            for (int mt = 0; mt < 2; ++mt) {
                acc[mt][nt] = __builtin_amdgcn_mfma_f32_16x16x32_f16(ah[mt], bh, acc[mt][nt], 0, 0, 0);
                acc[mt][nt] = __builtin_amdgcn_mfma_f32_16x16x32_f16(ah[mt], bl, acc[mt][nt], 0, 0, 0);
                acc[mt][nt] = __builtin_amdgcn_mfma_f32_16x16x32_f16(al[mt], bh, acc[mt][nt], 0, 0, 0);
                acc[mt][nt] = __builtin_amdgcn_mfma_f32_16x16x32_f16(al[mt], bl, acc[mt][nt], 0, 0, 0);
            }
        }
    }
    // ---- p part: kc 8..9 (pu, pd)
#pragma unroll
    for (int h = 0; h < 2; ++h) {
        f16x8 ah[2], al[2];
#pragma unroll
        for (int mt = 0; mt < 2; ++mt) {
            ah[mt] = *(const f16x8*)(pm_hi + aP[mt] + h * 32);
            al[mt] = *(const f16x8*)(pm_lo + aP[mt] + h * 32);
        }
#pragma unroll
        for (int nt = 0; nt < 4; ++nt) {
            f16x8 bh = *(const f16x8*)(Bhw + (size_t)(8 + h) * 8192 + nt * 512);
            f16x8 bl = *(const f16x8*)(Blw + (size_t)(8 + h) * 8192 + nt * 512);
#pragma unroll
            for (int mt = 0; mt < 2; ++mt) {
                acc[mt][nt] = __builtin_amdgcn_mfma_f32_16x16x32_f16(ah[mt], bh, acc[mt][nt], 0, 0, 0);
                acc[mt][nt] = __builtin_amdgcn_mfma_f32_16x16x32_f16(ah[mt], bl, acc[mt][nt], 0, 0, 0);
                acc[mt][nt] = __builtin_amdgcn_mfma_f32_16x16x32_f16(al[mt], bh, acc[mt][nt], 0, 0, 0);
                acc[mt][nt] = __builtin_amdgcn_mfma_f32_16x16x32_f16(al[mt], bl, acc[mt][nt], 0, 0, 0);
            }
        }
    }

    __syncthreads();   // all A reads complete before in-place rewrite

    // ---- epilogue
#pragma unroll
    for (int mt = 0; mt < 2; ++mt) {
#pragma unroll
        for (int nt = 0; nt < 4; ++nt) {
            const int n  = n0 + nt * 16 + m16;
            const float zv = Zsh[(size_t)(wb + mt) * 256 + n];
            const int rowbase = (wb + mt) * 16 + quad * 4;
#pragma unroll
            for (int reg = 0; reg < 4; ++reg) {
                const int idx = (rowbase + reg) * 256 + n;
                float t = fast_tanh(acc[mt][nt][reg] + zv);
                if (!is_final) t += (float)s_hi[idx] + (float)s_lo[idx];
                _Float16 hi, lo; split16(t, hi, lo);
                s_hi[idx] = hi;
                s_lo[idx] = lo;
            }
        }
    }
}

// ---------------------------------------------------------------------------
// Orbitals: reconstruct s from hi/lo; write orb (B,2,16(det),8(j),8(i))
// ---------------------------------------------------------------------------
__global__ __launch_bounds__(256) void k_orb(
    const float* __restrict__ r, const float* __restrict__ a,
    const _Float16* __restrict__ s_hi, const _Float16* __restrict__ s_lo,
    const float* __restrict__ wuW, const float* __restrict__ wub,
    const float* __restrict__ wdW, const float* __restrict__ wdb,
    float* __restrict__ orb)
{
    const int b   = blockIdx.x;
    const int tid = threadIdx.x;
    __shared__ float sF[16][256];
    __shared__ float envl[16];
    {
        const _Float16* sh = s_hi + (size_t)b * 4096;
        const _Float16* sl = s_lo + (size_t)b * 4096;
        float* sFF = &sF[0][0];
        for (int t = tid; t < 4096; t += 256)
            sFF[t] = (float)sh[t] + (float)sl[t];
    }
    if (tid < 16) {
        float ex = 0.f;
#pragma unroll
        for (int at = 0; at < 4; ++at) {
            float dx = r[b * 48 + tid * 3 + 0] - a[at * 3 + 0];
            float dy = r[b * 48 + tid * 3 + 1] - a[at * 3 + 1];
            float dz = r[b * 48 + tid * 3 + 2] - a[at * 3 + 2];
            ex += __expf(-sqrtf(dx * dx + dy * dy + dz * dz));
        }
        envl[tid] = ex;
    }
    __syncthreads();

    const int spin = tid >> 7;
    const int c    = tid & 127;
    const float* Wm = spin ? wdW : wuW;
    const float* bm = spin ? wdb : wub;
    const int e0 = spin * 8;
    float acc[8];
    const float bias = bm[c];
#pragma unroll
    for (int e = 0; e < 8; ++e) acc[e] = bias;
    for (int k = 0; k < 256; k += 4) {
        float w0 = Wm[(k + 0) * 128 + c];
        float w1 = Wm[(k + 1) * 128 + c];
        float w2 = Wm[(k + 2) * 128 + c];
        float w3 = Wm[(k + 3) * 128 + c];
#pragma unroll
        for (int e = 0; e < 8; ++e) {
            float4 s4 = *(const float4*)&sF[e0 + e][k];
            acc[e] += s4.x * w0 + s4.y * w1 + s4.z * w2 + s4.w * w3;
        }
    }
    const int d = c & 15, jrow = c >> 4;
    float out[8];
#pragma unroll
    for (int e = 0; e < 8; ++e) out[e] = acc[e] * envl[e0 + e];
    float* dst = orb + ((size_t)((b * 2 + spin) * 16 + d) * 8 + jrow) * 8;
    *(float4*)dst       = make_float4(out[0], out[1], out[2], out[3]);
    *(float4*)(dst + 4) = make_float4(out[4], out[5], out[6], out[7]);
}

// ---------------------------------------------------------------------------
// slogdet of 8x8 + det-combine + logsumexp
// ---------------------------------------------------------------------------
__device__ __forceinline__ void slogdet8(float M[8][8], float& sgn_out, float& ld_out) {
    float sgn = 1.f, ld = 0.f;
#pragma unroll
    for (int k = 0; k < 8; ++k) {
        float best = fabsf(M[k][k]);
        int p = k;
#pragma unroll
        for (int rr = k + 1; rr < 8; ++rr) {
            float v = fabsf(M[rr][k]);
            if (v > best) { best = v; p = rr; }
        }
        if (p != k) sgn = -sgn;
#pragma unroll
        for (int rr = k + 1; rr < 8; ++rr) {
            bool sw = (rr == p);
#pragma unroll
            for (int cc = k; cc < 8; ++cc) {
                float x = M[k][cc], y = M[rr][cc];
                M[k][cc]  = sw ? y : x;
                M[rr][cc] = sw ? x : y;
            }
        }
        float piv = M[k][k];
        if (piv < 0.f) sgn = -sgn;
        ld += logf(fabsf(piv));
        float inv = 1.f / piv;
#pragma unroll
        for (int rr = k + 1; rr < 8; ++rr) {
            float f = M[rr][k] * inv;
#pragma unroll
            for (int cc = k + 1; cc < 8; ++cc) M[rr][cc] -= f * M[k][cc];
        }
    }
    sgn_out = sgn; ld_out = ld;
}

__global__ __launch_bounds__(256) void k_det(
    const float* __restrict__ orb, const float* __restrict__ wfW,
    float* __restrict__ out)
{
    const int g = blockIdx.x * 256 + threadIdx.x;
    const int b = g >> 4, d = g & 15;
    float M[8][8];
    const float* src = orb + (size_t)((b * 2 + 0) * 16 + d) * 64;
#pragma unroll
    for (int rr = 0; rr < 8; ++rr) {
        float4 v0 = *(const float4*)&src[rr * 8];
        float4 v1 = *(const float4*)&src[rr * 8 + 4];
        M[rr][0] = v0.x; M[rr][1] = v0.y; M[rr][2] = v0.z; M[rr][3] = v0.w;
        M[rr][4] = v1.x; M[rr][5] = v1.y; M[rr][6] = v1.z; M[rr][7] = v1.w;
    }
    float s1, l1; slogdet8(M, s1, l1);
    src = orb + (size_t)((b * 2 + 1) * 16 + d) * 64;
#pragma unroll
    for (int rr = 0; rr < 8; ++rr) {
        float4 v0 = *(const float4*)&src[rr * 8];
        float4 v1 = *(const float4*)&src[rr * 8 + 4];
        M[rr][0] = v0.x; M[rr][1] = v0.y; M[rr][2] = v0.z; M[rr][3] = v0.w;
        M[rr][4] = v1.x; M[rr][5] = v1.y; M[rr][6] = v1.z; M[rr][7] = v1.w;
    }
    float s2, l2; slogdet8(M, s2, l2);
    float sgn = s1 * s2;
    float ld  = l1 + l2;

    float m = ld;
    m = fmaxf(m, __shfl_xor(m, 1));
    m = fmaxf(m, __shfl_xor(m, 2));
    m = fmaxf(m, __shfl_xor(m, 4));
    m = fmaxf(m, __shfl_xor(m, 8));
    float sub = sgn * __expf(ld - m) * wfW[d];
    sub += __shfl_xor(sub, 1);
    sub += __shfl_xor(sub, 2);
    sub += __shfl_xor(sub, 4);
    sub += __shfl_xor(sub, 8);
    if (d == 0) out[b] = logf(fabsf(sub)) + m;
}

// ---------------------------------------------------------------------------
extern "C" void kernel_launch(void* const* d_in, const int* in_sizes, int n_in,
                              void* d_out, int out_size, void* d_ws, size_t ws_size,
                              hipStream_t stream) {
    (void)in_sizes; (void)n_in; (void)out_size; (void)ws_size;
    const float* r   = (const float*)d_in[0];
    const float* a   = (const float*)d_in[1];
    const float* sW0 = (const float*)d_in[2];
    const float* sb0 = (const float*)d_in[3];
    const float* sW  = (const float*)d_in[4];
    const float* sb  = (const float*)d_in[5];
    const float* pW0 = (const float*)d_in[6];
    const float* pb0 = (const float*)d_in[7];
    const float* pW  = (const float*)d_in[8];
    const float* pb  = (const float*)d_in[9];
    const float* vW  = (const float*)d_in[10];
    const float* vb  = (const float*)d_in[11];
    const float* wuW = (const float*)d_in[12];
    const float* wub = (const float*)d_in[13];
    const float* wdW = (const float*)d_in[14];
    const float* wdb = (const float*)d_in[15];
    const float* wfW = (const float*)d_in[16];
    float* out = (float*)d_out;

    // workspace layout (bytes), total 79,249,408 (< 79,691,776 known-safe)
    char* wsb = (char*)d_ws;
    _Float16* s_hi  = (_Float16*)(wsb + 0);          // 16,777,216
    _Float16* s_lo  = (_Float16*)(wsb + 16777216);   // 16,777,216
    _Float16* pm_hi = (_Float16*)(wsb + 33554432);   // 20,971,520 (5 stages)
    _Float16* pm_lo = (_Float16*)(wsb + 54525952);   // 20,971,520
    float*    Zsh   = (float*)   (wsb + 75497472);   //  2,097,152
    _Float16* Bhi   = (_Float16*)(wsb + 77594624);   //    819,200
    _Float16* Blo   = (_Float16*)(wsb + 78413824);   //    819,200
    _Float16* pBhi  = (_Float16*)(wsb + 79233024);   //      8,192
    _Float16* pBlo  = (_Float16*)(wsb + 79241216);   //      8,192
    float*    orb   = (float*)   (wsb + 33554432);   // alias pm_hi (dead by k_orb)

    k_prep_w<<<50, 256, 0, stream>>>(sW, vW, Bhi, Blo);
    k_prep_p<<<4, 128, 0, stream>>>(pW, pBhi, pBlo);
    k_pstream<<<NB, 1024, 0, stream>>>(r, pW0, pb0, pb, pBhi, pBlo, pm_hi, pm_lo);
    k_s0<<<NB, 256, 0, stream>>>(r, a, sW0, sb0, s_hi, s_lo);
    for (int l = 0; l < 4; ++l) {
        k_shared<<<NB / 8, 512, 0, stream>>>(s_hi, s_lo, sW + (size_t)l * 212992,
                                             sb + l * 256, Zsh);
        k_gemm<<<NB / 2, 256, 0, stream>>>(s_hi, s_lo,
                                           pm_hi + (size_t)l * PM_STAGE,
                                           pm_lo + (size_t)l * PM_STAGE,
                                           Bhi + (size_t)l * BPK_L,
                                           Blo + (size_t)l * BPK_L,
                                           Zsh, 0);
    }
    k_shared<<<NB / 8, 512, 0, stream>>>(s_hi, s_lo, vW, vb, Zsh);
    k_gemm<<<NB / 2, 256, 0, stream>>>(s_hi, s_lo,
                                       pm_hi + (size_t)4 * PM_STAGE,
                                       pm_lo + (size_t)4 * PM_STAGE,
                                       Bhi + (size_t)4 * BPK_L,
                                       Blo + (size_t)4 * BPK_L,
                                       Zsh, 1);
    k_orb<<<NB, 256, 0, stream>>>(r, a, s_hi, s_lo, wuW, wub, wdW, wdb, orb);
    k_det<<<NB / 16, 256, 0, stream>>>(orb, wfW, out);
}

// Round 9
// 654.761 us; speedup vs baseline: 3.0179x; 1.0248x over previous
//
#include <hip/hip_runtime.h>
#include <math.h>

#define NB 2048
#define PM_STAGE 2097152   // elements per pmeans stage (2048*16*2*32)
#define BPK_L    81920     // elements per packed weight layer (10*16*64*8)

typedef float    f32x4 __attribute__((ext_vector_type(4)));
typedef _Float16 f16x8 __attribute__((ext_vector_type(8)));

__device__ __forceinline__ float fast_tanh(float x) {
    float ax = fabsf(x);
    float e  = __expf(2.0f * ax);
    float t  = 1.0f - 2.0f / (e + 1.0f);
    return copysignf(t, x);
}

__device__ __forceinline__ void split16(float x, _Float16& hi, _Float16& lo) {
    hi = (_Float16)x;
    lo = (_Float16)(x - (float)hi);
}

// ---------------------------------------------------------------------------
// One-time weight pack -> f16 hi/lo B-fragments for the PER-ELECTRON part only
// (A-features: [s 0..255 | pu 256..287 | pd 288..319] -> W rows f / 768+ / 800+).
// Bpk[l][kc(10)][nt(16)][lane(64)][j(8)]; layers 0..3 = sW[l], 4 = vW.
// ---------------------------------------------------------------------------
__global__ __launch_bounds__(256) void k_prep_w(
    const float* __restrict__ sW, const float* __restrict__ vW,
    _Float16* __restrict__ Bhi, _Float16* __restrict__ Blo)
{
    const int blk = blockIdx.x;       // l*10 + kc
    const int l   = blk / 10;
    const int kc  = blk % 10;
    const float* Wsrc = (l < 4) ? (sW + (size_t)l * 212992) : vW;
    const int lane = threadIdx.x & 63;
    const int sub  = threadIdx.x >> 6;
    const size_t base = (size_t)l * BPK_L + (size_t)kc * 8192;
#pragma unroll
    for (int ntl = 0; ntl < 4; ++ntl) {
        const int nt = sub * 4 + ntl;
        const int n  = nt * 16 + (lane & 15);
#pragma unroll
        for (int j = 0; j < 8; ++j) {
            const int f = kc * 32 + (lane >> 4) * 8 + j;   // 0..319
            int row;
            if (f < 256)      row = f;
            else if (f < 288) row = 768 + (f - 256);
            else              row = 800 + (f - 288);
            const float w = Wsrc[row * 256 + n];
            _Float16 hi, lo; split16(w, hi, lo);
            Bhi[base + (size_t)(nt * 64 + lane) * 8 + j] = hi;
            Blo[base + (size_t)(nt * 64 + lane) * 8 + j] = lo;
        }
    }
}

// ---------------------------------------------------------------------------
// One-time p-layer weight pack: pW (4,32,32) -> f16 hi/lo B-frags
// ---------------------------------------------------------------------------
__global__ __launch_bounds__(128) void k_prep_p(
    const float* __restrict__ pW,
    _Float16* __restrict__ pBhi, _Float16* __restrict__ pBlo)
{
    const int l    = blockIdx.x;
    const int nt   = threadIdx.x >> 6;
    const int lane = threadIdx.x & 63;
    const int m16  = lane & 15, quad = lane >> 4;
#pragma unroll
    for (int j = 0; j < 8; ++j) {
        float w = pW[l * 1024 + (quad * 8 + j) * 32 + nt * 16 + m16];
        _Float16 hi, lo; split16(w, hi, lo);
        pBhi[((size_t)l * 2 + nt) * 512 + lane * 8 + j] = hi;
        pBlo[((size_t)l * 2 + nt) * 512 + lane * 8 + j] = lo;
    }
}

// ---------------------------------------------------------------------------
// p-stream via split-f16 MFMA (3-term). Block = 1 walker = 1024 threads =
// 16 waves; wave = m-tile (16 pairs). State pst[feat][pair] in LDS; residual
// pcur fp32 in regs in D-layout. pmeans per stage: (B,16(j),2(h),32).
// ---------------------------------------------------------------------------
__global__ __launch_bounds__(1024) void k_pstream(
    const float* __restrict__ r,
    const float* __restrict__ pW0, const float* __restrict__ pb0,
    const float* __restrict__ pb,
    const _Float16* __restrict__ pBhi, const _Float16* __restrict__ pBlo,
    _Float16* __restrict__ pm_hi, _Float16* __restrict__ pm_lo)
{
    const int b    = blockIdx.x;
    const int tid  = threadIdx.x;
    const int lane = tid & 63;
    const int wv   = __builtin_amdgcn_readfirstlane(tid >> 6);  // m-tile 0..15
    const int m16  = lane & 15;
    const int quad = lane >> 4;

    __shared__ float rl[48];
    __shared__ float pst[32][257];

    if (tid < 48) rl[tid] = r[b * 48 + tid];
    __syncthreads();

    const int f0 = m16, f1 = m16 + 16;
    float pcur[2][4];   // [nt][reg], D-layout residual state

    // ---- layer 0
#pragma unroll
    for (int reg = 0; reg < 4; ++reg) {
        const int pair = wv * 16 + quad * 4 + reg;
        const int i = pair >> 4, j = pair & 15;
        float dx = rl[j * 3 + 0] - rl[i * 3 + 0];
        float dy = rl[j * 3 + 1] - rl[i * 3 + 1];
        float dz = rl[j * 3 + 2] - rl[i * 3 + 2];
        float ee = (i == j) ? 1.0f : 0.0f;
        float len = sqrtf((dx + ee) * (dx + ee) + (dy + ee) * (dy + ee) + (dz + ee) * (dz + ee));
#pragma unroll
        for (int nt = 0; nt < 2; ++nt) {
            const int k = nt ? f1 : f0;
            float acc = pb0[k] + dx * pW0[k] + dy * pW0[32 + k]
                      + dz * pW0[64 + k] + len * pW0[96 + k];
            float v = fast_tanh(acc);
            pcur[nt][reg] = v;
            pst[k][pair] = v;
        }
    }
    __syncthreads();

    // ---- stage-0 means
    {
        const int o = tid, mj = o >> 6, mh = (o >> 5) & 1, mk = o & 31;
        float s = 0.f;
#pragma unroll
        for (int i8 = 0; i8 < 8; ++i8) s += pst[mk][(mh * 8 + i8) * 16 + mj];
        _Float16 hi, lo; split16(s * 0.125f, hi, lo);
        pm_hi[(size_t)b * 1024 + o] = hi;
        pm_lo[(size_t)b * 1024 + o] = lo;
    }

    const int apair = wv * 16 + m16;
    for (int l = 0; l < 4; ++l) {
        f16x8 ah, al;
#pragma unroll
        for (int jj = 0; jj < 8; ++jj) {
            float v = pst[quad * 8 + jj][apair];
            _Float16 hi, lo; split16(v, hi, lo);
            ah[jj] = hi; al[jj] = lo;
        }
        const _Float16* bhp = pBhi + ((size_t)l * 2) * 512 + (size_t)lane * 8;
        const _Float16* blp = pBlo + ((size_t)l * 2) * 512 + (size_t)lane * 8;
        f32x4 acc0 = (f32x4){0.f, 0.f, 0.f, 0.f};
        f32x4 acc1 = (f32x4){0.f, 0.f, 0.f, 0.f};
        {
            f16x8 bh = *(const f16x8*)(bhp);
            f16x8 bl = *(const f16x8*)(blp);
            acc0 = __builtin_amdgcn_mfma_f32_16x16x32_f16(ah, bh, acc0, 0, 0, 0);
            acc0 = __builtin_amdgcn_mfma_f32_16x16x32_f16(ah, bl, acc0, 0, 0, 0);
            acc0 = __builtin_amdgcn_mfma_f32_16x16x32_f16(al, bh, acc0, 0, 0, 0);
            bh = *(const f16x8*)(bhp + 512);
            bl = *(const f16x8*)(blp + 512);
            acc1 = __builtin_amdgcn_mfma_f32_16x16x32_f16(ah, bh, acc1, 0, 0, 0);
            acc1 = __builtin_amdgcn_mfma_f32_16x16x32_f16(ah, bl, acc1, 0, 0, 0);
            acc1 = __builtin_amdgcn_mfma_f32_16x16x32_f16(al, bh, acc1, 0, 0, 0);
        }
        const float b0v = pb[l * 32 + f0];
        const float b1v = pb[l * 32 + f1];
        __syncthreads();   // all reads of old pst complete
#pragma unroll
        for (int reg = 0; reg < 4; ++reg) {
            const int pair = wv * 16 + quad * 4 + reg;
            pcur[0][reg] += fast_tanh(acc0[reg] + b0v);
            pcur[1][reg] += fast_tanh(acc1[reg] + b1v);
            pst[f0][pair] = pcur[0][reg];
            pst[f1][pair] = pcur[1][reg];
        }
        __syncthreads();   // new pst visible
        {
            const int o = tid, mj = o >> 6, mh = (o >> 5) & 1, mk = o & 31;
            float s = 0.f;
#pragma unroll
            for (int i8 = 0; i8 < 8; ++i8) s += pst[mk][(mh * 8 + i8) * 16 + mj];
            _Float16 hi, lo; split16(s * 0.125f, hi, lo);
            pm_hi[(size_t)(l + 1) * PM_STAGE + (size_t)b * 1024 + o] = hi;
            pm_lo[(size_t)(l + 1) * PM_STAGE + (size_t)b * 1024 + o] = lo;
        }
    }
}

// ---------------------------------------------------------------------------
// Layer 0: embedding + first s layer (fp32). Writes s hi/lo (f16).
// ---------------------------------------------------------------------------
__global__ __launch_bounds__(256) void k_s0(
    const float* __restrict__ r, const float* __restrict__ a,
    const float* __restrict__ sW0, const float* __restrict__ sb0,
    _Float16* __restrict__ s_hi, _Float16* __restrict__ s_lo)
{
    const int b   = blockIdx.x;
    const int tid = threadIdx.x;
    __shared__ float rl[48];
    __shared__ float al[12];
    __shared__ float pin[16][16][4];
    __shared__ float se[16][16];
    __shared__ float sm0[2][16];
    __shared__ float pm0[16][2][4];
    __shared__ float blk[16][56];

    if (tid < 48) rl[tid] = r[b * 48 + tid];
    if (tid >= 64 && tid < 76) al[tid - 64] = a[tid - 64];
    __syncthreads();
    {
        const int i = tid & 15, j = tid >> 4;
        float dx = rl[j * 3 + 0] - rl[i * 3 + 0];
        float dy = rl[j * 3 + 1] - rl[i * 3 + 1];
        float dz = rl[j * 3 + 2] - rl[i * 3 + 2];
        float ee = (i == j) ? 1.0f : 0.0f;
        float len = sqrtf((dx + ee) * (dx + ee) + (dy + ee) * (dy + ee) + (dz + ee) * (dz + ee));
        pin[j][i][0] = dx; pin[j][i][1] = dy; pin[j][i][2] = dz; pin[j][i][3] = len;
    }
    if (tid < 16) {
        const int e = tid;
#pragma unroll
        for (int at = 0; at < 4; ++at) {
            float dx = rl[e * 3 + 0] - al[at * 3 + 0];
            float dy = rl[e * 3 + 1] - al[at * 3 + 1];
            float dz = rl[e * 3 + 2] - al[at * 3 + 2];
            float ln = sqrtf(dx * dx + dy * dy + dz * dz);
            se[e][at * 4 + 0] = dx; se[e][at * 4 + 1] = dy;
            se[e][at * 4 + 2] = dz; se[e][at * 4 + 3] = ln;
        }
    }
    __syncthreads();
    if (tid < 32) {
        const int h = tid >> 4, f = tid & 15;
        float s = 0.f;
        for (int e = 0; e < 8; ++e) s += se[h * 8 + e][f];
        sm0[h][f] = s * 0.125f;
    }
    if (tid < 128) {
        const int j = tid >> 3, h = (tid >> 2) & 1, f = tid & 3;
        float s = 0.f;
        for (int i2 = 0; i2 < 8; ++i2) s += pin[j][h * 8 + i2][f];
        pm0[j][h][f] = s * 0.125f;
    }
    __syncthreads();
    for (int t = tid; t < 16 * 56; t += 256) {
        const int e = t / 56, k = t % 56;
        float v;
        if (k < 16)      v = se[e][k];
        else if (k < 32) v = sm0[0][k - 16];
        else if (k < 48) v = sm0[1][k - 32];
        else if (k < 52) v = pm0[e][0][k - 48];
        else             v = pm0[e][1][k - 52];
        blk[e][k] = v;
    }
    __syncthreads();

    const int n = tid;
    float acc[16];
#pragma unroll
    for (int e = 0; e < 16; ++e) acc[e] = sb0[n];
    for (int k = 0; k < 56; k += 4) {
        float w0 = sW0[(k + 0) * 256 + n];
        float w1 = sW0[(k + 1) * 256 + n];
        float w2 = sW0[(k + 2) * 256 + n];
        float w3 = sW0[(k + 3) * 256 + n];
#pragma unroll
        for (int e = 0; e < 16; ++e) {
            float4 s4 = *(const float4*)&blk[e][k];
            acc[e] += s4.x * w0 + s4.y * w1 + s4.z * w2 + s4.w * w3;
        }
    }
    _Float16* sh_b = s_hi + (size_t)b * 4096;
    _Float16* sl_b = s_lo + (size_t)b * 4096;
#pragma unroll
    for (int e = 0; e < 16; ++e) {
        float v = fast_tanh(acc[e]);
        _Float16 hi, lo; split16(v, hi, lo);
        sh_b[e * 256 + n] = hi;
        sl_b[e * 256 + n] = lo;
    }
}

// ---------------------------------------------------------------------------
// Shared (row-constant) part, exact fp32:
//   Zsh[b][n] = bias[n] + mu_b . W[256:512][:,n] + md_b . W[512:768][:,n]
// Block = 4 walkers, 256 threads, grid 512 (R8 post-mortem: 8-walker/grid-256
// gave only 2 waves/SIMD -> latency-bound on the 512 dependent L2 loads).
// ---------------------------------------------------------------------------
__global__ __launch_bounds__(256) void k_shared(
    const _Float16* __restrict__ s_hi, const _Float16* __restrict__ s_lo,
    const float* __restrict__ W, const float* __restrict__ bias,
    float* __restrict__ Zsh)
{
    const int b0  = blockIdx.x * 4;
    const int tid = threadIdx.x;
    __shared__ float mean[4][2][256];   // 8 KB

    {
        const int v0 = tid * 8;          // covers 4*2*256 = 2048 outputs
        const int w  = v0 >> 9, h = (v0 >> 8) & 1, k0 = v0 & 255;
        float acc[8] = {0.f, 0.f, 0.f, 0.f, 0.f, 0.f, 0.f, 0.f};
        for (int e = 0; e < 8; ++e) {
            const size_t base = ((size_t)(b0 + w) * 16 + h * 8 + e) * 256 + k0;
#pragma unroll
            for (int kk = 0; kk < 8; ++kk)
                acc[kk] += (float)s_hi[base + kk] + (float)s_lo[base + kk];
        }
#pragma unroll
        for (int kk = 0; kk < 8; ++kk) mean[w][h][k0 + kk] = acc[kk] * 0.125f;
    }
    __syncthreads();

    const int w2 = tid >> 6;
    const int n0 = (tid & 63) * 4;
    float4 z = make_float4(bias[n0], bias[n0 + 1], bias[n0 + 2], bias[n0 + 3]);
#pragma unroll 4
    for (int k = 0; k < 256; ++k) {
        const float mu = mean[w2][0][k];
        const float md = mean[w2][1][k];
        float4 wmu = *(const float4*)&W[(256 + k) * 256 + n0];
        float4 wmd = *(const float4*)&W[(512 + k) * 256 + n0];
        z.x += mu * wmu.x + md * wmd.x;
        z.y += mu * wmu.y + md * wmd.y;
        z.z += mu * wmu.z + md * wmd.z;
        z.w += mu * wmu.w + md * wmd.w;
    }
    *(float4*)&Zsh[(size_t)(b0 + w2) * 256 + n0] = z;
}

// ---------------------------------------------------------------------------
// Split-f16 MFMA s-layer (per-electron part, K=320), 3-term split.
// Block = 2 walkers (M=32), 4 waves; wave covers n-tiles wv*4..wv*4+3.
// ---------------------------------------------------------------------------
__global__ __launch_bounds__(256, 4) void k_gemm(
    _Float16* __restrict__ s_hi, _Float16* __restrict__ s_lo,
    const _Float16* __restrict__ pm_hi, const _Float16* __restrict__ pm_lo,
    const _Float16* __restrict__ Bhi, const _Float16* __restrict__ Blo,
    const float* __restrict__ Zsh,
    int is_final)
{
    const int tid  = threadIdx.x;
    const int lane = tid & 63;
    const int wv   = tid >> 6;
    const int m16  = lane & 15;
    const int quad = lane >> 4;
    const int wb   = blockIdx.x * 2;
    const int n0   = wv * 64;

    f32x4 acc[2][4];
#pragma unroll
    for (int mt = 0; mt < 2; ++mt)
#pragma unroll
        for (int nt = 0; nt < 4; ++nt) acc[mt][nt] = (f32x4){0.f, 0.f, 0.f, 0.f};

    int aS[2], aP[2];
#pragma unroll
    for (int mt = 0; mt < 2; ++mt) {
        aS[mt] = ((wb + mt) * 16 + m16) * 256 + quad * 8;
        aP[mt] = ((wb + mt) * 16 + m16) * 64  + quad * 8;
    }
    const _Float16* Bhw = Bhi + (size_t)(wv * 4) * 512 + (size_t)lane * 8;
    const _Float16* Blw = Blo + (size_t)(wv * 4) * 512 + (size_t)lane * 8;

    // ---- s part: kc 0..7
#pragma unroll
    for (int kc = 0; kc < 8; ++kc) {
        f16x8 ah[2], al[2];
#pragma unroll
        for (int mt = 0; mt < 2; ++mt) {
            ah[mt] = *(const f16x8*)(s_hi + aS[mt] + kc * 32);
            al[mt] = *(const f16x8*)(s_lo + aS[mt] + kc * 32);
        }
#pragma unroll
        for (int nt = 0; nt < 4; ++nt) {
            f16x8 bh = *(const f16x8*)(Bhw + (size_t)kc * 8192 + nt * 512);
            f16x8 bl = *(const f16x8*)(Blw + (size_t)kc * 8192 + nt * 512);
#pragma unroll
            for (int mt = 0; mt < 2; ++mt) {
                acc[mt][nt] = __builtin_amdgcn_mfma_f32_16x16x32_f16(ah[mt], bh, acc[mt][nt], 0, 0, 0);
                acc[mt][nt] = __builtin_amdgcn_mfma_f32_16x16x32_f16(ah[mt], bl, acc[mt][nt], 0, 0, 0);
                acc[mt][nt] = __builtin_amdgcn_mfma_f32_16x16x32_f16(al[mt], bh, acc[mt][nt], 0, 0, 0);
            }
        }
    }
    // ---- p part: kc 8..9 (pu, pd)
#pragma unroll
    for (int h = 0; h < 2; ++h) {
        f16x8 ah[2], al[2];
#pragma unroll
        for (int mt = 0; mt < 2; ++mt) {
            ah[mt] = *(const f16x8*)(pm_hi + aP[mt] + h * 32);
            al[mt] = *(const f16x8*)(pm_lo + aP[mt] + h * 32);
        }
#pragma unroll
        for (int nt = 0; nt < 4; ++nt) {
            f16x8 bh = *(const f16x8*)(Bhw + (size_t)(8 + h) * 8192 + nt * 512);
            f16x8 bl = *(const f16x8*)(Blw + (size_t)(8 + h) * 8192 + nt * 512);
#pragma unroll
            for (int mt = 0; mt < 2; ++mt) {
                acc[mt][nt] = __builtin_amdgcn_mfma_f32_16x16x32_f16(ah[mt], bh, acc[mt][nt], 0, 0, 0);
                acc[mt][nt] = __builtin_amdgcn_mfma_f32_16x16x32_f16(ah[mt], bl, acc[mt][nt], 0, 0, 0);
                acc[mt][nt] = __builtin_amdgcn_mfma_f32_16x16x32_f16(al[mt], bh, acc[mt][nt], 0, 0, 0);
            }
        }
    }

    __syncthreads();   // all A reads complete before in-place rewrite

    // ---- epilogue
#pragma unroll
    for (int mt = 0; mt < 2; ++mt) {
#pragma unroll
        for (int nt = 0; nt < 4; ++nt) {
            const int n  = n0 + nt * 16 + m16;
            const float zv = Zsh[(size_t)(wb + mt) * 256 + n];
            const int rowbase = (wb + mt) * 16 + quad * 4;
#pragma unroll
            for (int reg = 0; reg < 4; ++reg) {
                const int idx = (rowbase + reg) * 256 + n;
                float t = fast_tanh(acc[mt][nt][reg] + zv);
                if (!is_final) t += (float)s_hi[idx] + (float)s_lo[idx];
                _Float16 hi, lo; split16(t, hi, lo);
                s_hi[idx] = hi;
                s_lo[idx] = lo;
            }
        }
    }
}

// ---------------------------------------------------------------------------
// Orbitals: reconstruct s from hi/lo; write orb (B,2,16(det),8(j),8(i))
// ---------------------------------------------------------------------------
__global__ __launch_bounds__(256) void k_orb(
    const float* __restrict__ r, const float* __restrict__ a,
    const _Float16* __restrict__ s_hi, const _Float16* __restrict__ s_lo,
    const float* __restrict__ wuW, const float* __restrict__ wub,
    const float* __restrict__ wdW, const float* __restrict__ wdb,
    float* __restrict__ orb)
{
    const int b   = blockIdx.x;
    const int tid = threadIdx.x;
    __shared__ float sF[16][256];
    __shared__ float envl[16];
    {
        const _Float16* sh = s_hi + (size_t)b * 4096;
        const _Float16* sl = s_lo + (size_t)b * 4096;
        float* sFF = &sF[0][0];
        for (int t = tid; t < 4096; t += 256)
            sFF[t] = (float)sh[t] + (float)sl[t];
    }
    if (tid < 16) {
        float ex = 0.f;
#pragma unroll
        for (int at = 0; at < 4; ++at) {
            float dx = r[b * 48 + tid * 3 + 0] - a[at * 3 + 0];
            float dy = r[b * 48 + tid * 3 + 1] - a[at * 3 + 1];
            float dz = r[b * 48 + tid * 3 + 2] - a[at * 3 + 2];
            ex += __expf(-sqrtf(dx * dx + dy * dy + dz * dz));
        }
        envl[tid] = ex;
    }
    __syncthreads();

    const int spin = tid >> 7;
    const int c    = tid & 127;
    const float* Wm = spin ? wdW : wuW;
    const float* bm = spin ? wdb : wub;
    const int e0 = spin * 8;
    float acc[8];
    const float bias = bm[c];
#pragma unroll
    for (int e = 0; e < 8; ++e) acc[e] = bias;
    for (int k = 0; k < 256; k += 4) {
        float w0 = Wm[(k + 0) * 128 + c];
        float w1 = Wm[(k + 1) * 128 + c];
        float w2 = Wm[(k + 2) * 128 + c];
        float w3 = Wm[(k + 3) * 128 + c];
#pragma unroll
        for (int e = 0; e < 8; ++e) {
            float4 s4 = *(const float4*)&sF[e0 + e][k];
            acc[e] += s4.x * w0 + s4.y * w1 + s4.z * w2 + s4.w * w3;
        }
    }
    const int d = c & 15, jrow = c >> 4;
    float out[8];
#pragma unroll
    for (int e = 0; e < 8; ++e) out[e] = acc[e] * envl[e0 + e];
    float* dst = orb + ((size_t)((b * 2 + spin) * 16 + d) * 8 + jrow) * 8;
    *(float4*)dst       = make_float4(out[0], out[1], out[2], out[3]);
    *(float4*)(dst + 4) = make_float4(out[4], out[5], out[6], out[7]);
}

// ---------------------------------------------------------------------------
// slogdet of 8x8 + det-combine + logsumexp. 64-thread blocks (R8: 128 blocks
// of 256 left half the CUs idle).
// ---------------------------------------------------------------------------
__device__ __forceinline__ void slogdet8(float M[8][8], float& sgn_out, float& ld_out) {
    float sgn = 1.f, ld = 0.f;
#pragma unroll
    for (int k = 0; k < 8; ++k) {
        float best = fabsf(M[k][k]);
        int p = k;
#pragma unroll
        for (int rr = k + 1; rr < 8; ++rr) {
            float v = fabsf(M[rr][k]);
            if (v > best) { best = v; p = rr; }
        }
        if (p != k) sgn = -sgn;
#pragma unroll
        for (int rr = k + 1; rr < 8; ++rr) {
            bool sw = (rr == p);
#pragma unroll
            for (int cc = k; cc < 8; ++cc) {
                float x = M[k][cc], y = M[rr][cc];
                M[k][cc]  = sw ? y : x;
                M[rr][cc] = sw ? x : y;
            }
        }
        float piv = M[k][k];
        if (piv < 0.f) sgn = -sgn;
        ld += logf(fabsf(piv));
        float inv = 1.f / piv;
#pragma unroll
        for (int rr = k + 1; rr < 8; ++rr) {
            float f = M[rr][k] * inv;
#pragma unroll
            for (int cc = k + 1; cc < 8; ++cc) M[rr][cc] -= f * M[k][cc];
        }
    }
    sgn_out = sgn; ld_out = ld;
}

__global__ __launch_bounds__(64) void k_det(
    const float* __restrict__ orb, const float* __restrict__ wfW,
    float* __restrict__ out)
{
    const int g = blockIdx.x * 64 + threadIdx.x;
    const int b = g >> 4, d = g & 15;
    float M[8][8];
    const float* src = orb + (size_t)((b * 2 + 0) * 16 + d) * 64;
#pragma unroll
    for (int rr = 0; rr < 8; ++rr) {
        float4 v0 = *(const float4*)&src[rr * 8];
        float4 v1 = *(const float4*)&src[rr * 8 + 4];
        M[rr][0] = v0.x; M[rr][1] = v0.y; M[rr][2] = v0.z; M[rr][3] = v0.w;
        M[rr][4] = v1.x; M[rr][5] = v1.y; M[rr][6] = v1.z; M[rr][7] = v1.w;
    }
    float s1, l1; slogdet8(M, s1, l1);
    src = orb + (size_t)((b * 2 + 1) * 16 + d) * 64;
#pragma unroll
    for (int rr = 0; rr < 8; ++rr) {
        float4 v0 = *(const float4*)&src[rr * 8];
        float4 v1 = *(const float4*)&src[rr * 8 + 4];
        M[rr][0] = v0.x; M[rr][1] = v0.y; M[rr][2] = v0.z; M[rr][3] = v0.w;
        M[rr][4] = v1.x; M[rr][5] = v1.y; M[rr][6] = v1.z; M[rr][7] = v1.w;
    }
    float s2, l2; slogdet8(M, s2, l2);
    float sgn = s1 * s2;
    float ld  = l1 + l2;

    float m = ld;
    m = fmaxf(m, __shfl_xor(m, 1));
    m = fmaxf(m, __shfl_xor(m, 2));
    m = fmaxf(m, __shfl_xor(m, 4));
    m = fmaxf(m, __shfl_xor(m, 8));
    float sub = sgn * __expf(ld - m) * wfW[d];
    sub += __shfl_xor(sub, 1);
    sub += __shfl_xor(sub, 2);
    sub += __shfl_xor(sub, 4);
    sub += __shfl_xor(sub, 8);
    if (d == 0) out[b] = logf(fabsf(sub)) + m;
}

// ---------------------------------------------------------------------------
extern "C" void kernel_launch(void* const* d_in, const int* in_sizes, int n_in,
                              void* d_out, int out_size, void* d_ws, size_t ws_size,
                              hipStream_t stream) {
    (void)in_sizes; (void)n_in; (void)out_size; (void)ws_size;
    const float* r   = (const float*)d_in[0];
    const float* a   = (const float*)d_in[1];
    const float* sW0 = (const float*)d_in[2];
    const float* sb0 = (const float*)d_in[3];
    const float* sW  = (const float*)d_in[4];
    const float* sb  = (const float*)d_in[5];
    const float* pW0 = (const float*)d_in[6];
    const float* pb0 = (const float*)d_in[7];
    const float* pW  = (const float*)d_in[8];
    const float* pb  = (const float*)d_in[9];
    const float* vW  = (const float*)d_in[10];
    const float* vb  = (const float*)d_in[11];
    const float* wuW = (const float*)d_in[12];
    const float* wub = (const float*)d_in[13];
    const float* wdW = (const float*)d_in[14];
    const float* wdb = (const float*)d_in[15];
    const float* wfW = (const float*)d_in[16];
    float* out = (float*)d_out;

    // workspace layout (bytes), total 79,249,408 (< 79,691,776 known-safe)
    char* wsb = (char*)d_ws;
    _Float16* s_hi  = (_Float16*)(wsb + 0);          // 16,777,216
    _Float16* s_lo  = (_Float16*)(wsb + 16777216);   // 16,777,216
    _Float16* pm_hi = (_Float16*)(wsb + 33554432);   // 20,971,520 (5 stages)
    _Float16* pm_lo = (_Float16*)(wsb + 54525952);   // 20,971,520
    float*    Zsh   = (float*)   (wsb + 75497472);   //  2,097,152
    _Float16* Bhi   = (_Float16*)(wsb + 77594624);   //    819,200
    _Float16* Blo   = (_Float16*)(wsb + 78413824);   //    819,200
    _Float16* pBhi  = (_Float16*)(wsb + 79233024);   //      8,192
    _Float16* pBlo  = (_Float16*)(wsb + 79241216);   //      8,192
    float*    orb   = (float*)   (wsb + 33554432);   // alias pm_hi (dead by k_orb)

    k_prep_w<<<50, 256, 0, stream>>>(sW, vW, Bhi, Blo);
    k_prep_p<<<4, 128, 0, stream>>>(pW, pBhi, pBlo);
    k_pstream<<<NB, 1024, 0, stream>>>(r, pW0, pb0, pb, pBhi, pBlo, pm_hi, pm_lo);
    k_s0<<<NB, 256, 0, stream>>>(r, a, sW0, sb0, s_hi, s_lo);
    for (int l = 0; l < 4; ++l) {
        k_shared<<<NB / 4, 256, 0, stream>>>(s_hi, s_lo, sW + (size_t)l * 212992,
                                             sb + l * 256, Zsh);
        k_gemm<<<NB / 2, 256, 0, stream>>>(s_hi, s_lo,
                                           pm_hi + (size_t)l * PM_STAGE,
                                           pm_lo + (size_t)l * PM_STAGE,
                                           Bhi + (size_t)l * BPK_L,
                                           Blo + (size_t)l * BPK_L,
                                           Zsh, 0);
    }
    k_shared<<<NB / 4, 256, 0, stream>>>(s_hi, s_lo, vW, vb, Zsh);
    k_gemm<<<NB / 2, 256, 0, stream>>>(s_hi, s_lo,
                                       pm_hi + (size_t)4 * PM_STAGE,
                                       pm_lo + (size_t)4 * PM_STAGE,
                                       Bhi + (size_t)4 * BPK_L,
                                       Blo + (size_t)4 * BPK_L,
                                       Zsh, 1);
    k_orb<<<NB, 256, 0, stream>>>(r, a, s_hi, s_lo, wuW, wub, wdW, wdb, orb);
    k_det<<<512, 64, 0, stream>>>(orb, wfW, out);
}

// Round 11
// 647.417 us; speedup vs baseline: 3.0521x; 1.0113x over previous
//
#include <hip/hip_runtime.h>
#include <math.h>

#define NB 2048
#define PM_STAGE 2097152   // elements per pmeans stage (2048*16*2*32)
#define BPK_L    81920     // elements per packed weight layer (10*16*64*8)

typedef float    f32x4 __attribute__((ext_vector_type(4)));
typedef _Float16 f16x8 __attribute__((ext_vector_type(8)));

__device__ __forceinline__ float fast_tanh(float x) {
    float ax = fabsf(x);
    float e  = __expf(2.0f * ax);
    float t  = 1.0f - 2.0f / (e + 1.0f);
    return copysignf(t, x);
}

__device__ __forceinline__ void split16(float x, _Float16& hi, _Float16& lo) {
    hi = (_Float16)x;
    lo = (_Float16)(x - (float)hi);
}

// ---------------------------------------------------------------------------
// One-time weight pack -> f16 hi/lo B-fragments for the PER-ELECTRON part only
// (A-features: [s 0..255 | pu 256..287 | pd 288..319] -> W rows f / 768+ / 800+).
// Bpk[l][kc(10)][nt(16)][lane(64)][j(8)]; layers 0..3 = sW[l], 4 = vW.
// ---------------------------------------------------------------------------
__global__ __launch_bounds__(256) void k_prep_w(
    const float* __restrict__ sW, const float* __restrict__ vW,
    _Float16* __restrict__ Bhi, _Float16* __restrict__ Blo)
{
    const int blk = blockIdx.x;       // l*10 + kc
    const int l   = blk / 10;
    const int kc  = blk % 10;
    const float* Wsrc = (l < 4) ? (sW + (size_t)l * 212992) : vW;
    const int lane = threadIdx.x & 63;
    const int sub  = threadIdx.x >> 6;
    const size_t base = (size_t)l * BPK_L + (size_t)kc * 8192;
#pragma unroll
    for (int ntl = 0; ntl < 4; ++ntl) {
        const int nt = sub * 4 + ntl;
        const int n  = nt * 16 + (lane & 15);
#pragma unroll
        for (int j = 0; j < 8; ++j) {
            const int f = kc * 32 + (lane >> 4) * 8 + j;   // 0..319
            int row;
            if (f < 256)      row = f;
            else if (f < 288) row = 768 + (f - 256);
            else              row = 800 + (f - 288);
            const float w = Wsrc[row * 256 + n];
            _Float16 hi, lo; split16(w, hi, lo);
            Bhi[base + (size_t)(nt * 64 + lane) * 8 + j] = hi;
            Blo[base + (size_t)(nt * 64 + lane) * 8 + j] = lo;
        }
    }
}

// ---------------------------------------------------------------------------
// One-time p-layer weight pack: pW (4,32,32) -> f16 hi/lo B-frags
// ---------------------------------------------------------------------------
__global__ __launch_bounds__(128) void k_prep_p(
    const float* __restrict__ pW,
    _Float16* __restrict__ pBhi, _Float16* __restrict__ pBlo)
{
    const int l    = blockIdx.x;
    const int nt   = threadIdx.x >> 6;
    const int lane = threadIdx.x & 63;
    const int m16  = lane & 15, quad = lane >> 4;
#pragma unroll
    for (int j = 0; j < 8; ++j) {
        float w = pW[l * 1024 + (quad * 8 + j) * 32 + nt * 16 + m16];
        _Float16 hi, lo; split16(w, hi, lo);
        pBhi[((size_t)l * 2 + nt) * 512 + lane * 8 + j] = hi;
        pBlo[((size_t)l * 2 + nt) * 512 + lane * 8 + j] = lo;
    }
}

// ---------------------------------------------------------------------------
// p-stream via split-f16 MFMA (3-term). Block = 1 walker = 1024 threads =
// 16 waves; wave = m-tile (16 pairs). State pst[feat][pair] in LDS; residual
// pcur fp32 in regs in D-layout. pm output f16 hi/lo (R10 post-mortem: pm
// hi-only fails at 2.5 absmax — coherent rank-1 perturbation of orbitals).
// pmeans per stage: (B,16(j),2(h),32).
// ---------------------------------------------------------------------------
__global__ __launch_bounds__(1024) void k_pstream(
    const float* __restrict__ r,
    const float* __restrict__ pW0, const float* __restrict__ pb0,
    const float* __restrict__ pb,
    const _Float16* __restrict__ pBhi, const _Float16* __restrict__ pBlo,
    _Float16* __restrict__ pm_hi, _Float16* __restrict__ pm_lo)
{
    const int b    = blockIdx.x;
    const int tid  = threadIdx.x;
    const int lane = tid & 63;
    const int wv   = __builtin_amdgcn_readfirstlane(tid >> 6);  // m-tile 0..15
    const int m16  = lane & 15;
    const int quad = lane >> 4;

    __shared__ float rl[48];
    __shared__ float pst[32][257];

    if (tid < 48) rl[tid] = r[b * 48 + tid];
    __syncthreads();

    const int f0 = m16, f1 = m16 + 16;
    float pcur[2][4];   // [nt][reg], D-layout residual state

    // ---- layer 0
#pragma unroll
    for (int reg = 0; reg < 4; ++reg) {
        const int pair = wv * 16 + quad * 4 + reg;
        const int i = pair >> 4, j = pair & 15;
        float dx = rl[j * 3 + 0] - rl[i * 3 + 0];
        float dy = rl[j * 3 + 1] - rl[i * 3 + 1];
        float dz = rl[j * 3 + 2] - rl[i * 3 + 2];
        float ee = (i == j) ? 1.0f : 0.0f;
        float len = sqrtf((dx + ee) * (dx + ee) + (dy + ee) * (dy + ee) + (dz + ee) * (dz + ee));
#pragma unroll
        for (int nt = 0; nt < 2; ++nt) {
            const int k = nt ? f1 : f0;
            float acc = pb0[k] + dx * pW0[k] + dy * pW0[32 + k]
                      + dz * pW0[64 + k] + len * pW0[96 + k];
            float v = fast_tanh(acc);
            pcur[nt][reg] = v;
            pst[k][pair] = v;
        }
    }
    __syncthreads();

    // ---- stage-0 means
    {
        const int o = tid, mj = o >> 6, mh = (o >> 5) & 1, mk = o & 31;
        float s = 0.f;
#pragma unroll
        for (int i8 = 0; i8 < 8; ++i8) s += pst[mk][(mh * 8 + i8) * 16 + mj];
        _Float16 hi, lo; split16(s * 0.125f, hi, lo);
        pm_hi[(size_t)b * 1024 + o] = hi;
        pm_lo[(size_t)b * 1024 + o] = lo;
    }

    const int apair = wv * 16 + m16;
    for (int l = 0; l < 4; ++l) {
        f16x8 ah, al;
#pragma unroll
        for (int jj = 0; jj < 8; ++jj) {
            float v = pst[quad * 8 + jj][apair];
            _Float16 hi, lo; split16(v, hi, lo);
            ah[jj] = hi; al[jj] = lo;
        }
        const _Float16* bhp = pBhi + ((size_t)l * 2) * 512 + (size_t)lane * 8;
        const _Float16* blp = pBlo + ((size_t)l * 2) * 512 + (size_t)lane * 8;
        f32x4 acc0 = (f32x4){0.f, 0.f, 0.f, 0.f};
        f32x4 acc1 = (f32x4){0.f, 0.f, 0.f, 0.f};
        {
            f16x8 bh = *(const f16x8*)(bhp);
            f16x8 bl = *(const f16x8*)(blp);
            acc0 = __builtin_amdgcn_mfma_f32_16x16x32_f16(ah, bh, acc0, 0, 0, 0);
            acc0 = __builtin_amdgcn_mfma_f32_16x16x32_f16(ah, bl, acc0, 0, 0, 0);
            acc0 = __builtin_amdgcn_mfma_f32_16x16x32_f16(al, bh, acc0, 0, 0, 0);
            bh = *(const f16x8*)(bhp + 512);
            bl = *(const f16x8*)(blp + 512);
            acc1 = __builtin_amdgcn_mfma_f32_16x16x32_f16(ah, bh, acc1, 0, 0, 0);
            acc1 = __builtin_amdgcn_mfma_f32_16x16x32_f16(ah, bl, acc1, 0, 0, 0);
            acc1 = __builtin_amdgcn_mfma_f32_16x16x32_f16(al, bh, acc1, 0, 0, 0);
        }
        const float b0v = pb[l * 32 + f0];
        const float b1v = pb[l * 32 + f1];
        __syncthreads();   // all reads of old pst complete
#pragma unroll
        for (int reg = 0; reg < 4; ++reg) {
            const int pair = wv * 16 + quad * 4 + reg;
            pcur[0][reg] += fast_tanh(acc0[reg] + b0v);
            pcur[1][reg] += fast_tanh(acc1[reg] + b1v);
            pst[f0][pair] = pcur[0][reg];
            pst[f1][pair] = pcur[1][reg];
        }
        __syncthreads();   // new pst visible
        {
            const int o = tid, mj = o >> 6, mh = (o >> 5) & 1, mk = o & 31;
            float s = 0.f;
#pragma unroll
            for (int i8 = 0; i8 < 8; ++i8) s += pst[mk][(mh * 8 + i8) * 16 + mj];
            _Float16 hi, lo; split16(s * 0.125f, hi, lo);
            pm_hi[(size_t)(l + 1) * PM_STAGE + (size_t)b * 1024 + o] = hi;
            pm_lo[(size_t)(l + 1) * PM_STAGE + (size_t)b * 1024 + o] = lo;
        }
    }
}

// ---------------------------------------------------------------------------
// Layer 0: embedding + first s layer (fp32). Writes s hi/lo (f16).
// ---------------------------------------------------------------------------
__global__ __launch_bounds__(256) void k_s0(
    const float* __restrict__ r, const float* __restrict__ a,
    const float* __restrict__ sW0, const float* __restrict__ sb0,
    _Float16* __restrict__ s_hi, _Float16* __restrict__ s_lo)
{
    const int b   = blockIdx.x;
    const int tid = threadIdx.x;
    __shared__ float rl[48];
    __shared__ float al[12];
    __shared__ float pin[16][16][4];
    __shared__ float se[16][16];
    __shared__ float sm0[2][16];
    __shared__ float pm0[16][2][4];
    __shared__ float blk[16][56];

    if (tid < 48) rl[tid] = r[b * 48 + tid];
    if (tid >= 64 && tid < 76) al[tid - 64] = a[tid - 64];
    __syncthreads();
    {
        const int i = tid & 15, j = tid >> 4;
        float dx = rl[j * 3 + 0] - rl[i * 3 + 0];
        float dy = rl[j * 3 + 1] - rl[i * 3 + 1];
        float dz = rl[j * 3 + 2] - rl[i * 3 + 2];
        float ee = (i == j) ? 1.0f : 0.0f;
        float len = sqrtf((dx + ee) * (dx + ee) + (dy + ee) * (dy + ee) + (dz + ee) * (dz + ee));
        pin[j][i][0] = dx; pin[j][i][1] = dy; pin[j][i][2] = dz; pin[j][i][3] = len;
    }
    if (tid < 16) {
        const int e = tid;
#pragma unroll
        for (int at = 0; at < 4; ++at) {
            float dx = rl[e * 3 + 0] - al[at * 3 + 0];
            float dy = rl[e * 3 + 1] - al[at * 3 + 1];
            float dz = rl[e * 3 + 2] - al[at * 3 + 2];
            float ln = sqrtf(dx * dx + dy * dy + dz * dz);
            se[e][at * 4 + 0] = dx; se[e][at * 4 + 1] = dy;
            se[e][at * 4 + 2] = dz; se[e][at * 4 + 3] = ln;
        }
    }
    __syncthreads();
    if (tid < 32) {
        const int h = tid >> 4, f = tid & 15;
        float s = 0.f;
        for (int e = 0; e < 8; ++e) s += se[h * 8 + e][f];
        sm0[h][f] = s * 0.125f;
    }
    if (tid < 128) {
        const int j = tid >> 3, h = (tid >> 2) & 1, f = tid & 3;
        float s = 0.f;
        for (int i2 = 0; i2 < 8; ++i2) s += pin[j][h * 8 + i2][f];
        pm0[j][h][f] = s * 0.125f;
    }
    __syncthreads();
    for (int t = tid; t < 16 * 56; t += 256) {
        const int e = t / 56, k = t % 56;
        float v;
        if (k < 16)      v = se[e][k];
        else if (k < 32) v = sm0[0][k - 16];
        else if (k < 48) v = sm0[1][k - 32];
        else if (k < 52) v = pm0[e][0][k - 48];
        else             v = pm0[e][1][k - 52];
        blk[e][k] = v;
    }
    __syncthreads();

    const int n = tid;
    float acc[16];
#pragma unroll
    for (int e = 0; e < 16; ++e) acc[e] = sb0[n];
    for (int k = 0; k < 56; k += 4) {
        float w0 = sW0[(k + 0) * 256 + n];
        float w1 = sW0[(k + 1) * 256 + n];
        float w2 = sW0[(k + 2) * 256 + n];
        float w3 = sW0[(k + 3) * 256 + n];
#pragma unroll
        for (int e = 0; e < 16; ++e) {
            float4 s4 = *(const float4*)&blk[e][k];
            acc[e] += s4.x * w0 + s4.y * w1 + s4.z * w2 + s4.w * w3;
        }
    }
    _Float16* sh_b = s_hi + (size_t)b * 4096;
    _Float16* sl_b = s_lo + (size_t)b * 4096;
#pragma unroll
    for (int e = 0; e < 16; ++e) {
        float v = fast_tanh(acc[e]);
        _Float16 hi, lo; split16(v, hi, lo);
        sh_b[e * 256 + n] = hi;
        sl_b[e * 256 + n] = lo;
    }
}

// ---------------------------------------------------------------------------
// Shared (row-constant) part, exact fp32:
//   Zsh[b][n] = bias[n] + mu_b . W[256:512][:,n] + md_b . W[512:768][:,n]
// Block = 4 walkers, 256 threads, grid 512.
// ---------------------------------------------------------------------------
__global__ __launch_bounds__(256) void k_shared(
    const _Float16* __restrict__ s_hi, const _Float16* __restrict__ s_lo,
    const float* __restrict__ W, const float* __restrict__ bias,
    float* __restrict__ Zsh)
{
    const int b0  = blockIdx.x * 4;
    const int tid = threadIdx.x;
    __shared__ float mean[4][2][256];   // 8 KB

    {
        const int v0 = tid * 8;          // covers 4*2*256 = 2048 outputs
        const int w  = v0 >> 9, h = (v0 >> 8) & 1, k0 = v0 & 255;
        float acc[8] = {0.f, 0.f, 0.f, 0.f, 0.f, 0.f, 0.f, 0.f};
        for (int e = 0; e < 8; ++e) {
            const size_t base = ((size_t)(b0 + w) * 16 + h * 8 + e) * 256 + k0;
#pragma unroll
            for (int kk = 0; kk < 8; ++kk)
                acc[kk] += (float)s_hi[base + kk] + (float)s_lo[base + kk];
        }
#pragma unroll
        for (int kk = 0; kk < 8; ++kk) mean[w][h][k0 + kk] = acc[kk] * 0.125f;
    }
    __syncthreads();

    const int w2 = tid >> 6;
    const int n0 = (tid & 63) * 4;
    float4 z = make_float4(bias[n0], bias[n0 + 1], bias[n0 + 2], bias[n0 + 3]);
#pragma unroll 4
    for (int k = 0; k < 256; ++k) {
        const float mu = mean[w2][0][k];
        const float md = mean[w2][1][k];
        float4 wmu = *(const float4*)&W[(256 + k) * 256 + n0];
        float4 wmd = *(const float4*)&W[(512 + k) * 256 + n0];
        z.x += mu * wmu.x + md * wmd.x;
        z.y += mu * wmu.y + md * wmd.y;
        z.z += mu * wmu.z + md * wmd.z;
        z.w += mu * wmu.w + md * wmd.w;
    }
    *(float4*)&Zsh[(size_t)(b0 + w2) * 256 + n0] = z;
}

// ---------------------------------------------------------------------------
// Split-f16 MFMA s-layer (per-electron part, K=320), 3-term split.
// R11: block = 4 walkers, 512 threads = 8 waves = 2 wave-groups; both
// wave-groups stream the SAME B addresses (L1 dedup) and grid halves to 512
// -> B L2 traffic per dispatch 655 -> 328 MB. Numerics identical to R9.
// ---------------------------------------------------------------------------
__global__ __launch_bounds__(512, 4) void k_gemm(
    _Float16* __restrict__ s_hi, _Float16* __restrict__ s_lo,
    const _Float16* __restrict__ pm_hi, const _Float16* __restrict__ pm_lo,
    const _Float16* __restrict__ Bhi, const _Float16* __restrict__ Blo,
    const float* __restrict__ Zsh,
    int is_final)
{
    const int tid  = threadIdx.x;
    const int lane = tid & 63;
    const int wv   = tid >> 6;        // 0..7
    const int wg   = wv >> 2;         // walker group (2 walkers each)
    const int wv4  = wv & 3;          // n-tile group
    const int m16  = lane & 15;
    const int quad = lane >> 4;
    const int wb   = blockIdx.x * 4 + wg * 2;
    const int n0   = wv4 * 64;

    f32x4 acc[2][4];
#pragma unroll
    for (int mt = 0; mt < 2; ++mt)
#pragma unroll
        for (int nt = 0; nt < 4; ++nt) acc[mt][nt] = (f32x4){0.f, 0.f, 0.f, 0.f};

    int aS[2], aP[2];
#pragma unroll
    for (int mt = 0; mt < 2; ++mt) {
        aS[mt] = ((wb + mt) * 16 + m16) * 256 + quad * 8;
        aP[mt] = ((wb + mt) * 16 + m16) * 64  + quad * 8;
    }
    const _Float16* Bhw = Bhi + (size_t)(wv4 * 4) * 512 + (size_t)lane * 8;
    const _Float16* Blw = Blo + (size_t)(wv4 * 4) * 512 + (size_t)lane * 8;

    // ---- s part: kc 0..7
#pragma unroll
    for (int kc = 0; kc < 8; ++kc) {
        f16x8 ah[2], al[2];
#pragma unroll
        for (int mt = 0; mt < 2; ++mt) {
            ah[mt] = *(const f16x8*)(s_hi + aS[mt] + kc * 32);
            al[mt] = *(const f16x8*)(s_lo + aS[mt] + kc * 32);
        }
#pragma unroll
        for (int nt = 0; nt < 4; ++nt) {
            f16x8 bh = *(const f16x8*)(Bhw + (size_t)kc * 8192 + nt * 512);
            f16x8 bl = *(const f16x8*)(Blw + (size_t)kc * 8192 + nt * 512);
#pragma unroll
            for (int mt = 0; mt < 2; ++mt) {
                acc[mt][nt] = __builtin_amdgcn_mfma_f32_16x16x32_f16(ah[mt], bh, acc[mt][nt], 0, 0, 0);
                acc[mt][nt] = __builtin_amdgcn_mfma_f32_16x16x32_f16(ah[mt], bl, acc[mt][nt], 0, 0, 0);
                acc[mt][nt] = __builtin_amdgcn_mfma_f32_16x16x32_f16(al[mt], bh, acc[mt][nt], 0, 0, 0);
            }
        }
    }
    // ---- p part: kc 8..9 (pu, pd), pm hi/lo 3-term
#pragma unroll
    for (int h = 0; h < 2; ++h) {
        f16x8 ah[2], al[2];
#pragma unroll
        for (int mt = 0; mt < 2; ++mt) {
            ah[mt] = *(const f16x8*)(pm_hi + aP[mt] + h * 32);
            al[mt] = *(const f16x8*)(pm_lo + aP[mt] + h * 32);
        }
#pragma unroll
        for (int nt = 0; nt < 4; ++nt) {
            f16x8 bh = *(const f16x8*)(Bhw + (size_t)(8 + h) * 8192 + nt * 512);
            f16x8 bl = *(const f16x8*)(Blw + (size_t)(8 + h) * 8192 + nt * 512);
#pragma unroll
            for (int mt = 0; mt < 2; ++mt) {
                acc[mt][nt] = __builtin_amdgcn_mfma_f32_16x16x32_f16(ah[mt], bh, acc[mt][nt], 0, 0, 0);
                acc[mt][nt] = __builtin_amdgcn_mfma_f32_16x16x32_f16(ah[mt], bl, acc[mt][nt], 0, 0, 0);
                acc[mt][nt] = __builtin_amdgcn_mfma_f32_16x16x32_f16(al[mt], bh, acc[mt][nt], 0, 0, 0);
            }
        }
    }

    __syncthreads();   // all A reads complete before in-place rewrite

    // ---- epilogue
#pragma unroll
    for (int mt = 0; mt < 2; ++mt) {
#pragma unroll
        for (int nt = 0; nt < 4; ++nt) {
            const int n  = n0 + nt * 16 + m16;
            const float zv = Zsh[(size_t)(wb + mt) * 256 + n];
            const int rowbase = (wb + mt) * 16 + quad * 4;
#pragma unroll
            for (int reg = 0; reg < 4; ++reg) {
                const int idx = (rowbase + reg) * 256 + n;
                float t = fast_tanh(acc[mt][nt][reg] + zv);
                if (!is_final) t += (float)s_hi[idx] + (float)s_lo[idx];
                _Float16 hi, lo; split16(t, hi, lo);
                s_hi[idx] = hi;
                s_lo[idx] = lo;
            }
        }
    }
}

// ---------------------------------------------------------------------------
// Orbitals: reconstruct s from hi/lo; write orb (B,2,16(det),8(j),8(i))
// ---------------------------------------------------------------------------
__global__ __launch_bounds__(256) void k_orb(
    const float* __restrict__ r, const float* __restrict__ a,
    const _Float16* __restrict__ s_hi, const _Float16* __restrict__ s_lo,
    const float* __restrict__ wuW, const float* __restrict__ wub,
    const float* __restrict__ wdW, const float* __restrict__ wdb,
    float* __restrict__ orb)
{
    const int b   = blockIdx.x;
    const int tid = threadIdx.x;
    __shared__ float sF[16][256];
    __shared__ float envl[16];
    {
        const _Float16* sh = s_hi + (size_t)b * 4096;
        const _Float16* sl = s_lo + (size_t)b * 4096;
        float* sFF = &sF[0][0];
        for (int t = tid; t < 4096; t += 256)
            sFF[t] = (float)sh[t] + (float)sl[t];
    }
    if (tid < 16) {
        float ex = 0.f;
#pragma unroll
        for (int at = 0; at < 4; ++at) {
            float dx = r[b * 48 + tid * 3 + 0] - a[at * 3 + 0];
            float dy = r[b * 48 + tid * 3 + 1] - a[at * 3 + 1];
            float dz = r[b * 48 + tid * 3 + 2] - a[at * 3 + 2];
            ex += __expf(-sqrtf(dx * dx + dy * dy + dz * dz));
        }
        envl[tid] = ex;
    }
    __syncthreads();

    const int spin = tid >> 7;
    const int c    = tid & 127;
    const float* Wm = spin ? wdW : wuW;
    const float* bm = spin ? wdb : wub;
    const int e0 = spin * 8;
    float acc[8];
    const float bias = bm[c];
#pragma unroll
    for (int e = 0; e < 8; ++e) acc[e] = bias;
    for (int k = 0; k < 256; k += 4) {
        float w0 = Wm[(k + 0) * 128 + c];
        float w1 = Wm[(k + 1) * 128 + c];
        float w2 = Wm[(k + 2) * 128 + c];
        float w3 = Wm[(k + 3) * 128 + c];
#pragma unroll
        for (int e = 0; e < 8; ++e) {
            float4 s4 = *(const float4*)&sF[e0 + e][k];
            acc[e] += s4.x * w0 + s4.y * w1 + s4.z * w2 + s4.w * w3;
        }
    }
    const int d = c & 15, jrow = c >> 4;
    float out[8];
#pragma unroll
    for (int e = 0; e < 8; ++e) out[e] = acc[e] * envl[e0 + e];
    float* dst = orb + ((size_t)((b * 2 + spin) * 16 + d) * 8 + jrow) * 8;
    *(float4*)dst       = make_float4(out[0], out[1], out[2], out[3]);
    *(float4*)(dst + 4) = make_float4(out[4], out[5], out[6], out[7]);
}

// ---------------------------------------------------------------------------
// slogdet of 8x8 + det-combine + logsumexp
// ---------------------------------------------------------------------------
__device__ __forceinline__ void slogdet8(float M[8][8], float& sgn_out, float& ld_out) {
    float sgn = 1.f, ld = 0.f;
#pragma unroll
    for (int k = 0; k < 8; ++k) {
        float best = fabsf(M[k][k]);
        int p = k;
#pragma unroll
        for (int rr = k + 1; rr < 8; ++rr) {
            float v = fabsf(M[rr][k]);
            if (v > best) { best = v; p = rr; }
        }
        if (p != k) sgn = -sgn;
#pragma unroll
        for (int rr = k + 1; rr < 8; ++rr) {
            bool sw = (rr == p);
#pragma unroll
            for (int cc = k; cc < 8; ++cc) {
                float x = M[k][cc], y = M[rr][cc];
                M[k][cc]  = sw ? y : x;
                M[rr][cc] = sw ? x : y;
            }
        }
        float piv = M[k][k];
        if (piv < 0.f) sgn = -sgn;
        ld += logf(fabsf(piv));
        float inv = 1.f / piv;
#pragma unroll
        for (int rr = k + 1; rr < 8; ++rr) {
            float f = M[rr][k] * inv;
#pragma unroll
            for (int cc = k + 1; cc < 8; ++cc) M[rr][cc] -= f * M[k][cc];
        }
    }
    sgn_out = sgn; ld_out = ld;
}

__global__ __launch_bounds__(64) void k_det(
    const float* __restrict__ orb, const float* __restrict__ wfW,
    float* __restrict__ out)
{
    const int g = blockIdx.x * 64 + threadIdx.x;
    const int b = g >> 4, d = g & 15;
    float M[8][8];
    const float* src = orb + (size_t)((b * 2 + 0) * 16 + d) * 64;
#pragma unroll
    for (int rr = 0; rr < 8; ++rr) {
        float4 v0 = *(const float4*)&src[rr * 8];
        float4 v1 = *(const float4*)&src[rr * 8 + 4];
        M[rr][0] = v0.x; M[rr][1] = v0.y; M[rr][2] = v0.z; M[rr][3] = v0.w;
        M[rr][4] = v1.x; M[rr][5] = v1.y; M[rr][6] = v1.z; M[rr][7] = v1.w;
    }
    float s1, l1; slogdet8(M, s1, l1);
    src = orb + (size_t)((b * 2 + 1) * 16 + d) * 64;
#pragma unroll
    for (int rr = 0; rr < 8; ++rr) {
        float4 v0 = *(const float4*)&src[rr * 8];
        float4 v1 = *(const float4*)&src[rr * 8 + 4];
        M[rr][0] = v0.x; M[rr][1] = v0.y; M[rr][2] = v0.z; M[rr][3] = v0.w;
        M[rr][4] = v1.x; M[rr][5] = v1.y; M[rr][6] = v1.z; M[rr][7] = v1.w;
    }
    float s2, l2; slogdet8(M, s2, l2);
    float sgn = s1 * s2;
    float ld  = l1 + l2;

    float m = ld;
    m = fmaxf(m, __shfl_xor(m, 1));
    m = fmaxf(m, __shfl_xor(m, 2));
    m = fmaxf(m, __shfl_xor(m, 4));
    m = fmaxf(m, __shfl_xor(m, 8));
    float sub = sgn * __expf(ld - m) * wfW[d];
    sub += __shfl_xor(sub, 1);
    sub += __shfl_xor(sub, 2);
    sub += __shfl_xor(sub, 4);
    sub += __shfl_xor(sub, 8);
    if (d == 0) out[b] = logf(fabsf(sub)) + m;
}

// ---------------------------------------------------------------------------
extern "C" void kernel_launch(void* const* d_in, const int* in_sizes, int n_in,
                              void* d_out, int out_size, void* d_ws, size_t ws_size,
                              hipStream_t stream) {
    (void)in_sizes; (void)n_in; (void)out_size; (void)ws_size;
    const float* r   = (const float*)d_in[0];
    const float* a   = (const float*)d_in[1];
    const float* sW0 = (const float*)d_in[2];
    const float* sb0 = (const float*)d_in[3];
    const float* sW  = (const float*)d_in[4];
    const float* sb  = (const float*)d_in[5];
    const float* pW0 = (const float*)d_in[6];
    const float* pb0 = (const float*)d_in[7];
    const float* pW  = (const float*)d_in[8];
    const float* pb  = (const float*)d_in[9];
    const float* vW  = (const float*)d_in[10];
    const float* vb  = (const float*)d_in[11];
    const float* wuW = (const float*)d_in[12];
    const float* wub = (const float*)d_in[13];
    const float* wdW = (const float*)d_in[14];
    const float* wdb = (const float*)d_in[15];
    const float* wfW = (const float*)d_in[16];
    float* out = (float*)d_out;

    // workspace layout (bytes), total 79,249,408 (< 79,691,776 known-safe)
    char* wsb = (char*)d_ws;
    _Float16* s_hi  = (_Float16*)(wsb + 0);          // 16,777,216
    _Float16* s_lo  = (_Float16*)(wsb + 16777216);   // 16,777,216
    _Float16* pm_hi = (_Float16*)(wsb + 33554432);   // 20,971,520 (5 stages)
    _Float16* pm_lo = (_Float16*)(wsb + 54525952);   // 20,971,520
    float*    Zsh   = (float*)   (wsb + 75497472);   //  2,097,152
    _Float16* Bhi   = (_Float16*)(wsb + 77594624);   //    819,200
    _Float16* Blo   = (_Float16*)(wsb + 78413824);   //    819,200
    _Float16* pBhi  = (_Float16*)(wsb + 79233024);   //      8,192
    _Float16* pBlo  = (_Float16*)(wsb + 79241216);   //      8,192
    float*    orb   = (float*)   (wsb + 33554432);   // alias pm_hi (dead by k_orb)

    k_prep_w<<<50, 256, 0, stream>>>(sW, vW, Bhi, Blo);
    k_prep_p<<<4, 128, 0, stream>>>(pW, pBhi, pBlo);
    k_pstream<<<NB, 1024, 0, stream>>>(r, pW0, pb0, pb, pBhi, pBlo, pm_hi, pm_lo);
    k_s0<<<NB, 256, 0, stream>>>(r, a, sW0, sb0, s_hi, s_lo);
    for (int l = 0; l < 4; ++l) {
        k_shared<<<NB / 4, 256, 0, stream>>>(s_hi, s_lo, sW + (size_t)l * 212992,
                                             sb + l * 256, Zsh);
        k_gemm<<<NB / 4, 512, 0, stream>>>(s_hi, s_lo,
                                           pm_hi + (size_t)l * PM_STAGE,
                                           pm_lo + (size_t)l * PM_STAGE,
                                           Bhi + (size_t)l * BPK_L,
                                           Blo + (size_t)l * BPK_L,
                                           Zsh, 0);
    }
    k_shared<<<NB / 4, 256, 0, stream>>>(s_hi, s_lo, vW, vb, Zsh);
    k_gemm<<<NB / 4, 512, 0, stream>>>(s_hi, s_lo,
                                       pm_hi + (size_t)4 * PM_STAGE,
                                       pm_lo + (size_t)4 * PM_STAGE,
                                       Bhi + (size_t)4 * BPK_L,
                                       Blo + (size_t)4 * BPK_L,
                                       Zsh, 1);
    k_orb<<<NB, 256, 0, stream>>>(r, a, s_hi, s_lo, wuW, wub, wdW, wdb, orb);
    k_det<<<512, 64, 0, stream>>>(orb, wfW, out);
}